// Round 15
// baseline (267.731 us; speedup 1.0000x reference)
//
#include <hip/hip_runtime.h>
#include <hip/hip_bf16.h>

typedef unsigned short u16;
typedef __attribute__((ext_vector_type(8))) short bf16x8;
typedef __attribute__((ext_vector_type(4))) float f32x4;
typedef __attribute__((ext_vector_type(4))) unsigned short u16x4;

#define B_  4
#define T_  1024
#define H_  1024
#define NH_ 16
#define HS_ 64
#define FF_ 4096
#define M_  (B_*T_)
#define QKV_S 3072

__device__ __forceinline__ u16 f2bf(float f){
  union { float f; unsigned u; } v; v.f = f;
  unsigned r = v.u + 0x7fffu + ((v.u >> 16) & 1u);
  return (u16)(r >> 16);
}
__device__ __forceinline__ float bf2f(u16 h){
  union { unsigned u; float f; } v; v.u = ((unsigned)h) << 16;
  return v.f;
}
__device__ __forceinline__ unsigned pack2bf(float a, float b){
  __hip_bfloat162 h = __float22bfloat162_rn(make_float2(a, b));
  union { __hip_bfloat162 h; unsigned u; } c; c.h = h;
  return c.u;
}

__device__ __forceinline__ void gload_lds16(const void* g, void* l){
  __builtin_amdgcn_global_load_lds(
      (const __attribute__((address_space(1))) unsigned int*)g,
      (__attribute__((address_space(3))) unsigned int*)l,
      16, 0, 0);
}

// ---------------- 64x64 transpose tile body (fp32 -> bf16)
__device__ __forceinline__ void trans_tile(const float* __restrict__ W,
                                           u16* __restrict__ Wt, int K, int N,
                                           int k0, int n0, int tid)
{
  __shared__ u16 tile[64][68];
  #pragma unroll
  for (int it = 0; it < 4; ++it){
    int ci = tid + it * 256;
    int kr = ci >> 4, nc = ci & 15;
    float4 f = *(const float4*)(W + (size_t)(k0 + kr) * N + n0 + nc * 4);
    tile[kr][nc*4+0] = f2bf(f.x);
    tile[kr][nc*4+1] = f2bf(f.y);
    tile[kr][nc*4+2] = f2bf(f.z);
    tile[kr][nc*4+3] = f2bf(f.w);
  }
  __syncthreads();
  #pragma unroll
  for (int it = 0; it < 4; ++it){
    int co = tid + it * 256;
    int nr = co >> 4, kc = co & 15;
    u16x4 o;
    o[0] = tile[kc*4+0][nr];
    o[1] = tile[kc*4+1][nr];
    o[2] = tile[kc*4+2][nr];
    o[3] = tile[kc*4+3][nr];
    *(u16x4*)(Wt + (size_t)(n0 + nr) * K + k0 + kc * 4) = o;
  }
}

// ---------------- fused 4x HxH weight transpose (Wq,Wk,Wv -> WqkvT; Wo -> WoT)
__global__ __launch_bounds__(256) void trans_qkvo_k(
    const float* __restrict__ Wq, const float* __restrict__ Wk,
    const float* __restrict__ Wv, const float* __restrict__ Wo,
    u16* __restrict__ WqkvT, u16* __restrict__ WoT)
{
  const int z = blockIdx.z;
  const float* src = (z == 0) ? Wq : (z == 1) ? Wk : (z == 2) ? Wv : Wo;
  u16* dst = (z == 3) ? WoT : (WqkvT + (size_t)z * 1024 * 1024);
  trans_tile(src, dst, H_, H_, blockIdx.y * 64, blockIdx.x * 64, threadIdx.x);
}

// ---------------- generic transpose (Wfc, Wpr)
__global__ __launch_bounds__(256) void transpose_cvt(const float* __restrict__ W,
                                                     u16* __restrict__ Wt, int K, int N)
{
  trans_tile(W, Wt, K, N, blockIdx.y * 64, blockIdx.x * 64, threadIdx.x);
}

// ---------------- per-head V transpose: vtg[bh][d][t] = v[b,t,h,d]
__global__ __launch_bounds__(256) void vtrans_k(const u16* __restrict__ qkv,
                                                u16* __restrict__ vtg)
{
  __shared__ u16 tile[64][72];
  const int bh = blockIdx.y, tt = blockIdx.x * 64;
  const int b = bh >> 4, h = bh & 15;
  const size_t src = (size_t)b * T_ * QKV_S + h * HS_ + 2048;
  const int tid = threadIdx.x;
  #pragma unroll
  for (int it = 0; it < 2; ++it){
    int ci = tid + it * 256;
    int r = ci >> 3, c = ci & 7;
    bf16x8 vvv = *(const bf16x8*)(qkv + src + (size_t)(tt + r) * QKV_S + c * 8);
    *(bf16x8*)&tile[r][c * 8] = vvv;
  }
  __syncthreads();
  #pragma unroll
  for (int it = 0; it < 2; ++it){
    int co = tid + it * 256;
    int d = co >> 3, c = co & 7;
    bf16x8 ov;
    #pragma unroll
    for (int j = 0; j < 8; ++j) ov[j] = (short)tile[c * 8 + j][d];
    *(bf16x8*)(vtg + (size_t)bh * HS_ * T_ + (size_t)d * T_ + tt + c * 8) = ov;
  }
}

// ---------------- small prep: bias concat (3072) + rope cos/sin table (32768)
__global__ void prep_small_k(const float* __restrict__ a, const float* __restrict__ b,
                             const float* __restrict__ c, float* __restrict__ o,
                             float* __restrict__ tab){
  int i = blockIdx.x * 256 + threadIdx.x;
  if (i < QKV_S){
    o[i] = (i < 1024) ? a[i] : (i < 2048) ? b[i - 1024] : c[i - 2048];
  } else {
    int j = i - QKV_S;
    if (j < T_ * 32){
      int t = j >> 5, f = j & 31;
      float inv = powf(10000.0f, -(float)f * (1.0f / 32.0f));
      float ang = (float)t * inv;
      tab[j*2+0] = cosf(ang);
      tab[j*2+1] = sinf(ang);
    }
  }
}

// ---------------- LayerNorm: fp32 in -> bf16 out, one row (1024) per block
__global__ __launch_bounds__(256) void ln_kernel(const float* __restrict__ x,
    const float* __restrict__ w, const float* __restrict__ bgain,
    u16* __restrict__ out)
{
  const int row = blockIdx.x;
  const int t = threadIdx.x;
  float4 vv = ((const float4*)(x + (size_t)row * H_))[t];
  float s  = vv.x + vv.y + vv.z + vv.w;
  float s2 = vv.x*vv.x + vv.y*vv.y + vv.z*vv.z + vv.w*vv.w;
  #pragma unroll
  for (int mm = 1; mm < 64; mm <<= 1){ s += __shfl_xor(s, mm); s2 += __shfl_xor(s2, mm); }
  __shared__ float red[8];
  int wid = t >> 6;
  if ((t & 63) == 0){ red[wid] = s; red[4 + wid] = s2; }
  __syncthreads();
  s  = red[0] + red[1] + red[2] + red[3];
  s2 = red[4] + red[5] + red[6] + red[7];
  float mu  = s * (1.0f / H_);
  float var = s2 * (1.0f / H_) - mu * mu;
  float rin = rsqrtf(var + 1e-5f);
  float4 wv = ((const float4*)w)[t];
  float4 bv = ((const float4*)bgain)[t];
  u16x4 ov;
  ov[0] = f2bf((vv.x - mu) * rin * wv.x + bv.x);
  ov[1] = f2bf((vv.y - mu) * rin * wv.y + bv.y);
  ov[2] = f2bf((vv.z - mu) * rin * wv.z + bv.z);
  ov[3] = f2bf((vv.w - mu) * rin * wv.w + bv.w);
  ((u16x4*)(out + (size_t)row * H_))[t] = ov;
}

// ---------------- GEMM (BM=256, BN=256): 128x64 wave tiles (42.7 FLOP/LDS-B).
// SWAPPED operands: lane owns row=lrow, 4 consecutive cols.
// EPI 1: bf16 gelu(tanh/exp2).  EPI 2: bf16 out with fused RoPE on cols<2048
// (q cols additionally scaled to exp2 domain).
template<int EPI>
__global__ __launch_bounds__(512, 2) void gemm_big_kernel(
    const u16* __restrict__ A, const u16* __restrict__ Bt,
    const float* __restrict__ bias, const float* __restrict__ rtab,
    void* __restrict__ Cout, int M, int N, int K)
{
  __shared__ __attribute__((aligned(16))) u16 As[3][256 * 32];
  __shared__ __attribute__((aligned(16))) u16 Bs[3][256 * 32];
  const int tid  = threadIdx.x;
  const int lane = tid & 63;
  const int wid  = tid >> 6;           // 0..7
  const int wm = wid >> 2, wn = wid & 3;
  const int lrow = lane & 15, lkg = lane >> 4;

  const int gx  = gridDim.x;
  const int nwg = gx * gridDim.y;
  const int wg  = blockIdx.y * gx + blockIdx.x;
  const int nx  = nwg >> 3;
  const int swz = (wg & 7) * nx + (wg >> 3);
  const int m0 = (swz / gx) * 256, n0 = (swz % gx) * 256;

  const int r0 = tid >> 2;             // 0..127
  const int c0 = tid & 3;
  const int s0 = c0 ^ ((r0 >> 1) & 3);
  const u16* Asrc0 = A  + (size_t)(m0 + r0) * K + s0 * 8;
  const u16* Asrc1 = Asrc0 + (size_t)128 * K;
  const u16* Bsrc0 = Bt + (size_t)(n0 + r0) * K + s0 * 8;
  const u16* Bsrc1 = Bsrc0 + (size_t)128 * K;
  const int d0 = tid * 8;
  const int d1 = (tid + 512) * 8;

  int aoff[8], boff[4];
  #pragma unroll
  for (int mi = 0; mi < 8; ++mi){
    int r = wm*128 + mi*16 + lrow;
    aoff[mi] = (r*4 + (lkg ^ ((r >> 1) & 3))) * 16;
  }
  #pragma unroll
  for (int ni = 0; ni < 4; ++ni){
    int r = wn*64 + ni*16 + lrow;
    boff[ni] = (r*4 + (lkg ^ ((r >> 1) & 3))) * 16;
  }

  f32x4 acc[8][4] = {};
  const int NT = K >> 5;

  #pragma unroll
  for (int s = 0; s < 2; ++s){
    int k0 = s << 5;
    gload_lds16(Asrc0 + k0, &As[s][d0]);
    gload_lds16(Asrc1 + k0, &As[s][d1]);
    gload_lds16(Bsrc0 + k0, &Bs[s][d0]);
    gload_lds16(Bsrc1 + k0, &Bs[s][d1]);
  }

  int rs = 0, wsl = 2;
  for (int t = 0; t < NT; ++t){
    if (t < NT - 1) asm volatile("s_waitcnt vmcnt(4)" ::: "memory");
    else            asm volatile("s_waitcnt vmcnt(0)" ::: "memory");
    __builtin_amdgcn_s_barrier();

    const char* Ab = (const char*)&As[rs][0];
    const char* Bb = (const char*)&Bs[rs][0];
    rs = (rs + 1 == 3) ? 0 : rs + 1;

    bf16x8 af[8], bfr[4];
    #pragma unroll
    for (int mi = 0; mi < 8; ++mi)
      af[mi] = *(const bf16x8*)(Ab + aoff[mi]);
    #pragma unroll
    for (int ni = 0; ni < 4; ++ni)
      bfr[ni] = *(const bf16x8*)(Bb + boff[ni]);
    __builtin_amdgcn_sched_barrier(0);

    if (t + 2 < NT){
      int k0 = (t + 2) << 5;
      gload_lds16(Asrc0 + k0, &As[wsl][d0]);
      gload_lds16(Asrc1 + k0, &As[wsl][d1]);
      gload_lds16(Bsrc0 + k0, &Bs[wsl][d0]);
      gload_lds16(Bsrc1 + k0, &Bs[wsl][d1]);
    }
    wsl = (wsl + 1 == 3) ? 0 : wsl + 1;

    #pragma unroll
    for (int mi = 0; mi < 8; ++mi)
      #pragma unroll
      for (int ni = 0; ni < 4; ++ni)
        acc[mi][ni] = __builtin_amdgcn_mfma_f32_16x16x32_bf16(bfr[ni], af[mi], acc[mi][ni], 0, 0, 0);
  }

  #pragma unroll
  for (int mi = 0; mi < 8; ++mi){
    int row = m0 + wm*128 + mi*16 + lrow;
    #pragma unroll
    for (int ni = 0; ni < 4; ++ni){
      int col0 = n0 + wn*64 + ni*16 + lkg*4;
      float4 bv = *(const float4*)(bias + col0);
      float v0 = acc[mi][ni][0] + bv.x;
      float v1 = acc[mi][ni][1] + bv.y;
      float v2 = acc[mi][ni][2] + bv.z;
      float v3 = acc[mi][ni][3] + bv.w;
      if (EPI == 1){
        float u0 = 0.7978845608f * v0 + 0.0356774081f * v0 * v0 * v0;
        float u1 = 0.7978845608f * v1 + 0.0356774081f * v1 * v1 * v1;
        float u2 = 0.7978845608f * v2 + 0.0356774081f * v2 * v2 * v2;
        float u3 = 0.7978845608f * v3 + 0.0356774081f * v3 * v3 * v3;
        float e0 = exp2f(u0 * 2.8853900818f);
        float e1 = exp2f(u1 * 2.8853900818f);
        float e2 = exp2f(u2 * 2.8853900818f);
        float e3 = exp2f(u3 * 2.8853900818f);
        v0 = v0 - v0 / (e0 + 1.0f);
        v1 = v1 - v1 / (e1 + 1.0f);
        v2 = v2 - v2 / (e2 + 1.0f);
        v3 = v3 - v3 / (e3 + 1.0f);
      }
      if (EPI == 2){
        if (col0 < 2048){
          int tt = row & (T_ - 1);
          const float* rt = rtab + ((size_t)tt * 32 + ((col0 & 63) >> 1)) * 2;
          float cc0 = rt[0], ss0 = rt[1], cc1 = rt[2], ss1 = rt[3];
          float q0 = v0 * cc0 - v1 * ss0, q1 = v0 * ss0 + v1 * cc0;
          float q2 = v2 * cc1 - v3 * ss1, q3 = v2 * ss1 + v3 * cc1;
          if (col0 < 1024){
            const float qs = 0.125f * 1.44269504f;
            q0 *= qs; q1 *= qs; q2 *= qs; q3 *= qs;
          }
          v0 = q0; v1 = q1; v2 = q2; v3 = q3;
        }
      }
      uint2 ov;
      ov.x = pack2bf(v0, v1);
      ov.y = pack2bf(v2, v3);
      *(uint2*)((u16*)Cout + (size_t)row * N + col0) = ov;
    }
  }
}

// ---------------- GEMM (BM=64, BN=128): skinny-N GEMMs (Wo, Wpr).
// blockIdx.z = K-split slice (koff = z*K within row stride LD).
// OUT 0: fp32 + bias + residual.  OUT 1: bf16 partial (no bias), slice z at
// Cout + z*M*N.
template<int RING, int OUT>
__global__ __launch_bounds__(256, (RING == 3) ? 4 : 2) void gemm64_kernel(
    const u16* __restrict__ A, const u16* __restrict__ Bt,
    const float* __restrict__ bias, const float* __restrict__ res,
    void* __restrict__ Cout, int M, int N, int K, int LD)
{
  __shared__ __attribute__((aligned(16))) u16 As[RING][64 * 32];
  __shared__ __attribute__((aligned(16))) u16 Bs[RING][128 * 32];
  const int tid  = threadIdx.x;
  const int lane = tid & 63;
  const int wid  = tid >> 6;           // 0..3
  const int wm = wid >> 1, wn = wid & 1;
  const int lrow = lane & 15, lkg = lane >> 4;

  const int gx  = gridDim.x;           // N/128
  const int nwg = gx * gridDim.y;
  const int wg  = blockIdx.y * gx + blockIdx.x;
  const int nx  = nwg >> 3;
  const int swz = (wg & 7) * nx + (wg >> 3);
  const int m0 = (swz / gx) * 64, n0 = (swz % gx) * 128;
  const int koff = blockIdx.z * K;

  const int srow = tid >> 2;           // 0..63
  const int sdc  = tid & 3;
  const int scs  = sdc ^ ((srow >> 1) & 3);
  const u16* Asrc  = A  + (size_t)(m0 + srow) * LD + koff + scs * 8;
  const u16* Bsrc0 = Bt + (size_t)(n0 + srow) * LD + koff + scs * 8;
  const u16* Bsrc1 = Bsrc0 + (size_t)64 * LD;
  const int dA  = (srow * 4 + sdc) * 8;
  const int dB1 = dA + 64 * 32;

  int aoff[2], boff[4];
  #pragma unroll
  for (int mi = 0; mi < 2; ++mi){
    int r = wm*32 + mi*16 + lrow;
    aoff[mi] = (r*4 + (lkg ^ ((r >> 1) & 3))) * 16;
  }
  #pragma unroll
  for (int ni = 0; ni < 4; ++ni){
    int r = wn*64 + ni*16 + lrow;
    boff[ni] = (r*4 + (lkg ^ ((r >> 1) & 3))) * 16;
  }

  f32x4 acc[2][4] = {};
  const int NT = K >> 5;
  constexpr int DIST = RING - 1;

  #pragma unroll
  for (int s = 0; s < DIST; ++s){
    gload_lds16(Asrc  + (s << 5), &As[s][dA]);
    gload_lds16(Bsrc0 + (s << 5), &Bs[s][dA]);
    gload_lds16(Bsrc1 + (s << 5), &Bs[s][dB1]);
  }

  int rs = 0, wsl = DIST;
  for (int t = 0; t < NT; ++t){
    int cnt = NT - 1 - t; if (cnt > DIST - 1) cnt = DIST - 1;
    if constexpr (RING == 4){
      if (cnt >= 2)      asm volatile("s_waitcnt vmcnt(6)" ::: "memory");
      else if (cnt == 1) asm volatile("s_waitcnt vmcnt(3)" ::: "memory");
      else               asm volatile("s_waitcnt vmcnt(0)" ::: "memory");
    } else {  // RING == 3
      if (cnt >= 1)      asm volatile("s_waitcnt vmcnt(3)" ::: "memory");
      else               asm volatile("s_waitcnt vmcnt(0)" ::: "memory");
    }
    __builtin_amdgcn_s_barrier();

    const char* Ab = (const char*)&As[rs][0];
    const char* Bb = (const char*)&Bs[rs][0];
    rs = (rs + 1 == RING) ? 0 : rs + 1;

    bf16x8 af[2], bfr[4];
    #pragma unroll
    for (int mi = 0; mi < 2; ++mi)
      af[mi] = *(const bf16x8*)(Ab + aoff[mi]);
    #pragma unroll
    for (int ni = 0; ni < 4; ++ni)
      bfr[ni] = *(const bf16x8*)(Bb + boff[ni]);
    __builtin_amdgcn_sched_barrier(0);

    if (t + DIST < NT){
      int k0 = (t + DIST) << 5;
      gload_lds16(Asrc  + k0, &As[wsl][dA]);
      gload_lds16(Bsrc0 + k0, &Bs[wsl][dA]);
      gload_lds16(Bsrc1 + k0, &Bs[wsl][dB1]);
    }
    wsl = (wsl + 1 == RING) ? 0 : wsl + 1;

    #pragma unroll
    for (int mi = 0; mi < 2; ++mi)
      #pragma unroll
      for (int ni = 0; ni < 4; ++ni)
        acc[mi][ni] = __builtin_amdgcn_mfma_f32_16x16x32_bf16(bfr[ni], af[mi], acc[mi][ni], 0, 0, 0);
  }

  #pragma unroll
  for (int mi = 0; mi < 2; ++mi){
    int row = m0 + wm*32 + mi*16 + lrow;
    #pragma unroll
    for (int ni = 0; ni < 4; ++ni){
      int col0 = n0 + wn*64 + ni*16 + lkg*4;
      if (OUT == 0){
        float4 bv = *(const float4*)(bias + col0);
        float4 rv = *(const float4*)(res + (size_t)row * N + col0);
        float4 ov;
        ov.x = acc[mi][ni][0] + bv.x + rv.x;
        ov.y = acc[mi][ni][1] + bv.y + rv.y;
        ov.z = acc[mi][ni][2] + bv.z + rv.z;
        ov.w = acc[mi][ni][3] + bv.w + rv.w;
        *(float4*)((float*)Cout + (size_t)row * N + col0) = ov;
      } else {
        u16* outp = (u16*)Cout + (size_t)blockIdx.z * M * N;
        uint2 ov;
        ov.x = pack2bf(acc[mi][ni][0], acc[mi][ni][1]);
        ov.y = pack2bf(acc[mi][ni][2], acc[mi][ni][3]);
        *(uint2*)(outp + (size_t)row * N + col0) = ov;
      }
    }
  }
}

// ---------------- split-K reduce: out = p[z=0] + p[z=1] + bias + res  (fp32)
__global__ __launch_bounds__(256) void sk_reduce_k(const u16* __restrict__ p,
    const float* __restrict__ bias, const float* __restrict__ res,
    float* __restrict__ out)
{
  size_t e = ((size_t)blockIdx.x * 256 + threadIdx.x) * 8;
  int col = (int)(e & (H_ - 1));
  const size_t off = (size_t)M_ * H_;
  u16x4 a0 = *(const u16x4*)(p + e);
  u16x4 a1 = *(const u16x4*)(p + e + 4);
  u16x4 b0 = *(const u16x4*)(p + off + e);
  u16x4 b1 = *(const u16x4*)(p + off + e + 4);
  float4 bs0 = *(const float4*)(bias + col);
  float4 bs1 = *(const float4*)(bias + col + 4);
  float4 r0 = *(const float4*)(res + e);
  float4 r1 = *(const float4*)(res + e + 4);
  float4 o0, o1;
  o0.x = bf2f(a0[0]) + bf2f(b0[0]) + bs0.x + r0.x;
  o0.y = bf2f(a0[1]) + bf2f(b0[1]) + bs0.y + r0.y;
  o0.z = bf2f(a0[2]) + bf2f(b0[2]) + bs0.z + r0.z;
  o0.w = bf2f(a0[3]) + bf2f(b0[3]) + bs0.w + r0.w;
  o1.x = bf2f(a1[0]) + bf2f(b1[0]) + bs1.x + r1.x;
  o1.y = bf2f(a1[1]) + bf2f(b1[1]) + bs1.y + r1.y;
  o1.z = bf2f(a1[2]) + bf2f(b1[2]) + bs1.z + r1.z;
  o1.w = bf2f(a1[3]) + bf2f(b1[3]) + bs1.w + r1.w;
  *(float4*)(out + e)     = o0;
  *(float4*)(out + e + 4) = o1;
}

// ---------------- fused attention (swapped-operand form), 8 waves / 128 q-rows
__global__ __launch_bounds__(512, 4) void attn_kernel(
    const u16* __restrict__ qkv, const u16* __restrict__ vtg,
    u16* __restrict__ out)
{
  __shared__ u16 K_lds[3][64 * 64];
  __shared__ u16 VT_lds[3][64 * 64];
  __shared__ u16 P_lds[8][16 * 64];
  const int tid = threadIdx.x, lane = tid & 63, w = tid >> 6;   // w: 0..7
  const int lrow = lane & 15, lkg = lane >> 4;
  const int q0 = blockIdx.x * 128;
  const int bh = blockIdx.y, b = bh >> 4, h = bh & 15;
  const size_t baseq  = (size_t)b * T_ * QKV_S + h * HS_;
  const size_t basek  = baseq + 1024;
  const size_t basevt = (size_t)bh * HS_ * T_;
  const size_t baseo  = (size_t)b * T_ * H_ + h * HS_;
  const int qg = q0 + w * 16 + lrow;      // this lane's q row

  bf16x8 qa[2];
  {
    const u16* qp = qkv + baseq + (size_t)qg * QKV_S + lkg * 8;
    qa[0] = *(const bf16x8*)qp;
    qa[1] = *(const bf16x8*)(qp + 32);
  }

  const int r0 = tid >> 3, c0 = tid & 7, g0 = c0 ^ (r0 & 7);
  const u16* kap = qkv + basek + (size_t)r0 * QKV_S + g0 * 8;
  const u16* vap = vtg + basevt + (size_t)r0 * T_ + g0 * 8;
  const int kd = tid * 8;

  f32x4 o[4] = {};
  float mrun = -1e30f, lrun = 0.f;

  #pragma unroll
  for (int s = 0; s < 2; ++s){
    gload_lds16(kap + (size_t)s * 64 * QKV_S, &K_lds[s][kd]);
    gload_lds16(vap + s * 64,                 &VT_lds[s][kd]);
  }

  int rs = 0, wsl = 2;
  for (int t = 0; t < 16; ++t){
    const int kt = t << 6;
    if (t < 15) asm volatile("s_waitcnt vmcnt(2)" ::: "memory");
    else        asm volatile("s_waitcnt vmcnt(0)" ::: "memory");
    __builtin_amdgcn_s_barrier();
    __builtin_amdgcn_sched_barrier(0);

    if (t + 2 < 16){
      gload_lds16(kap + (size_t)(t + 2) * 64 * QKV_S, &K_lds[wsl][kd]);
      gload_lds16(vap + (t + 2) * 64,                 &VT_lds[wsl][kd]);
    }
    wsl = (wsl + 1 == 3) ? 0 : wsl + 1;

    const u16* Kc  = K_lds[rs];
    const u16* VTc = VT_lds[rs];
    rs = (rs + 1 == 3) ? 0 : rs + 1;

    f32x4 s[4];
    __builtin_amdgcn_s_setprio(1);
    #pragma unroll
    for (int mi = 0; mi < 4; ++mi){
      f32x4 c = {};
      #pragma unroll
      for (int ss = 0; ss < 2; ++ss){
        int r = mi * 16 + lrow;
        int off = r * 128 + (((ss * 4 + lkg) ^ (r & 7)) * 16);
        bf16x8 kb = *(const bf16x8*)((const char*)Kc + off);
        c = __builtin_amdgcn_mfma_f32_16x16x32_bf16(kb, qa[ss], c, 0, 0, 0);
      }
      s[mi] = c;
    }
    __builtin_amdgcn_s_setprio(0);

    float mt = fmaxf(fmaxf(fmaxf(s[0][0], s[0][1]), fmaxf(s[0][2], s[0][3])),
                     fmaxf(fmaxf(s[1][0], s[1][1]), fmaxf(s[1][2], s[1][3])));
    mt = fmaxf(mt, fmaxf(fmaxf(fmaxf(s[2][0], s[2][1]), fmaxf(s[2][2], s[2][3])),
                         fmaxf(fmaxf(s[3][0], s[3][1]), fmaxf(s[3][2], s[3][3]))));
    mt = fmaxf(mt, __shfl_xor(mt, 16));
    mt = fmaxf(mt, __shfl_xor(mt, 32));
    if (!__all(mt <= mrun + 8.f)){       // defer-max
      float mnew = fmaxf(mrun, mt);
      float fsc = exp2f(mrun - mnew);
      lrun *= fsc;
      #pragma unroll
      for (int nf = 0; nf < 4; ++nf){
        #pragma unroll
        for (int r = 0; r < 4; ++r) o[nf][r] *= fsc;
      }
      mrun = mnew;
    }

    float p[16];
    float ls = 0.f;
    #pragma unroll
    for (int mi = 0; mi < 4; ++mi){
      #pragma unroll
      for (int r = 0; r < 4; ++r){
        int key = kt + mi * 16 + lkg * 4 + r;
        float pv = exp2f(s[mi][r] - mrun);
        ls += pv;                          // denominator over ALL keys
        p[mi * 4 + r] = (key <= qg) ? pv : 0.f;
      }
    }
    ls += __shfl_xor(ls, 16);
    ls += __shfl_xor(ls, 32);
    lrun += ls;

    if (kt <= q0 + w * 16 + 15){
      char* pbase = (char*)&P_lds[w][0];
      const int rx = (lrow & 7) << 4;
      #pragma unroll
      for (int mi = 0; mi < 4; ++mi){
        uint2 pk;
        pk.x = pack2bf(p[mi*4+0], p[mi*4+1]);
        pk.y = pack2bf(p[mi*4+2], p[mi*4+3]);
        *(uint2*)(pbase + (lrow * 128 + ((mi * 32 + lkg * 8) ^ rx))) = pk;
      }
      __builtin_amdgcn_s_setprio(1);
      #pragma unroll
      for (int ss = 0; ss < 2; ++ss){
        bf16x8 pb = *(const bf16x8*)(pbase + (lrow * 128 + ((ss * 64 + lkg * 16) ^ rx)));
        #pragma unroll
        for (int nfd = 0; nfd < 4; ++nfd){
          int d = nfd * 16 + lrow;
          int off = d * 128 + (((ss * 4 + lkg) ^ (d & 7)) * 16);
          bf16x8 vb = *(const bf16x8*)((const char*)VTc + off);
          o[nfd] = __builtin_amdgcn_mfma_f32_16x16x32_bf16(vb, pb, o[nfd], 0, 0, 0);
        }
      }
      __builtin_amdgcn_s_setprio(0);
    }
  }

  float rl = 1.0f / lrun;
  #pragma unroll
  for (int nfd = 0; nfd < 4; ++nfd){
    uint2 ov;
    ov.x = pack2bf(o[nfd][0] * rl, o[nfd][1] * rl);
    ov.y = pack2bf(o[nfd][2] * rl, o[nfd][3] * rl);
    *(uint2*)(out + baseo + (size_t)qg * H_ + nfd * 16 + lkg * 4) = ov;
  }
}

extern "C" void kernel_launch(void* const* d_in, const int* in_sizes, int n_in,
                              void* d_out, int out_size, void* d_ws, size_t ws_size,
                              hipStream_t stream)
{
  (void)in_sizes; (void)n_in; (void)out_size; (void)ws_size;
  const float* x    = (const float*)d_in[0];
  const float* Wq   = (const float*)d_in[1];
  const float* bq   = (const float*)d_in[2];
  const float* Wk   = (const float*)d_in[3];
  const float* bk   = (const float*)d_in[4];
  const float* Wv   = (const float*)d_in[5];
  const float* bv   = (const float*)d_in[6];
  const float* Wo   = (const float*)d_in[7];
  const float* bo   = (const float*)d_in[8];
  const float* ln1w = (const float*)d_in[9];
  const float* ln1b = (const float*)d_in[10];
  const float* ln2w = (const float*)d_in[11];
  const float* ln2b = (const float*)d_in[12];
  const float* Wfc  = (const float*)d_in[13];
  const float* bfc  = (const float*)d_in[14];
  const float* Wpr  = (const float*)d_in[15];
  const float* bpr  = (const float*)d_in[16];

  char* ws = (char*)d_ws;
  u16*  WqkvT = (u16*)(ws + ((size_t) 0 << 20));   //  6MB; dead after QKV gemm
  u16*  WoT   = (u16*)(ws + ((size_t) 6 << 20));   //  2MB; dead after Wo gemm
  u16*  WfcT  = (u16*)(ws + ((size_t) 8 << 20));   //  8MB; dead after Wfc gemm
  u16*  skp   = (u16*)(ws + ((size_t) 0 << 20));   // 16MB split-K partials (reuses 0..16)
  u16*  WprT  = (u16*)(ws + ((size_t)16 << 20));   //  8MB [H][FF]
  u16*  h1    = (u16*)(ws + ((size_t)24 << 20));   //  8MB; reused as attnout
  u16*  qkvb  = (u16*)(ws + ((size_t)32 << 20));   // 24MB [M][3072]; dead after attn
  float* x1   = (float*)(ws + ((size_t)32 << 20)); // 16MB (reuses qkvb region)
  u16*  h2    = (u16*)(ws + ((size_t)48 << 20));   //  8MB (reuses qkvb region)
  float* bqkv = (float*)(ws + ((size_t)56 << 20)); // 12KB (dead before mb written)
  float* rtab = (float*)(ws + ((size_t)56 << 20) + (64 << 10)); // 256KB (dead before mb)
  u16*  vtg   = (u16*)(ws + ((size_t)57 << 20));   //  8MB (dead before mb)
  u16*  mb    = (u16*)(ws + ((size_t)56 << 20));   // 32MB (overwrites bqkv/rtab/vtg)
  u16*  attnout = h1;

  dim3 blk(256);
  dim3 gblk(512);

  // weights: transpose + bf16 (QKV concatenated; 4 HxH in one launch)
  trans_qkvo_k<<<dim3(H_/64, H_/64, 4), blk, 0, stream>>>(Wq, Wk, Wv, Wo, WqkvT, WoT);
  transpose_cvt<<<dim3(FF_/64, H_/64),  blk, 0, stream>>>(Wfc, WfcT, H_,  FF_);
  transpose_cvt<<<dim3(H_/64,  FF_/64), blk, 0, stream>>>(Wpr, WprT, FF_, H_);
  prep_small_k<<<dim3((QKV_S + T_*32 + 255)/256), blk, 0, stream>>>(bq, bk, bv, bqkv, rtab);

  // LN1
  ln_kernel<<<dim3(M_), blk, 0, stream>>>(x, ln1w, ln1b, h1);
  // fused QKV projection + RoPE (exp2-domain q scale) — 256x256 tiles
  gemm_big_kernel<2><<<dim3(QKV_S/256, M_/256), gblk, 0, stream>>>(h1, WqkvT, bqkv, rtab, qkvb, M_, QKV_S, H_);
  // per-head V transpose
  vtrans_k<<<dim3(T_/64, B_*NH_), blk, 0, stream>>>(qkvb, vtg);
  // attention — 8 waves, 128 q-rows/block
  attn_kernel<<<dim3(T_/128, B_*NH_), dim3(512), 0, stream>>>(qkvb, vtg, attnout);
  // out projection + residual -> x1 (fp32) — BM=64 grid 8x64 (2 blk/CU)
  gemm64_kernel<4,0><<<dim3(H_/128, M_/64), blk, 0, stream>>>(attnout, WoT, bo, x, x1, M_, H_, H_, H_);
  // LN2
  ln_kernel<<<dim3(M_), blk, 0, stream>>>(x1, ln2w, ln2b, h2);
  // MLP: Wfc 256x256 tiles; Wpr split-K=2 (4 blk/CU) -> bf16 partials -> reduce
  gemm_big_kernel<1><<<dim3(FF_/256, M_/256), gblk, 0, stream>>>(h2, WfcT, bfc, nullptr, mb, M_, FF_, H_);
  gemm64_kernel<3,1><<<dim3(H_/128, M_/64, 2), blk, 0, stream>>>(mb, WprT, nullptr, nullptr, skp, M_, H_, FF_/2, FF_);
  sk_reduce_k<<<dim3((M_*H_)/(256*8)), blk, 0, stream>>>(skp, bpr, x1, (float*)d_out);
}

// Round 16
// 250.407 us; speedup vs baseline: 1.0692x; 1.0692x over previous
//
#include <hip/hip_runtime.h>
#include <hip/hip_bf16.h>

typedef unsigned short u16;
typedef __attribute__((ext_vector_type(8))) short bf16x8;
typedef __attribute__((ext_vector_type(4))) float f32x4;
typedef __attribute__((ext_vector_type(4))) unsigned short u16x4;

#define B_  4
#define T_  1024
#define H_  1024
#define NH_ 16
#define HS_ 64
#define FF_ 4096
#define M_  (B_*T_)
#define QKV_S 3072

__device__ __forceinline__ u16 f2bf(float f){
  union { float f; unsigned u; } v; v.f = f;
  unsigned r = v.u + 0x7fffu + ((v.u >> 16) & 1u);
  return (u16)(r >> 16);
}
__device__ __forceinline__ float bf2f(u16 h){
  union { unsigned u; float f; } v; v.u = ((unsigned)h) << 16;
  return v.f;
}
__device__ __forceinline__ unsigned pack2bf(float a, float b){
  __hip_bfloat162 h = __float22bfloat162_rn(make_float2(a, b));
  union { __hip_bfloat162 h; unsigned u; } c; c.h = h;
  return c.u;
}

__device__ __forceinline__ void gload_lds16(const void* g, void* l){
  __builtin_amdgcn_global_load_lds(
      (const __attribute__((address_space(1))) unsigned int*)g,
      (__attribute__((address_space(3))) unsigned int*)l,
      16, 0, 0);
}

// ---------------- 64x64 transpose tile body (fp32 -> bf16)
__device__ __forceinline__ void trans_tile(const float* __restrict__ W,
                                           u16* __restrict__ Wt, int K, int N,
                                           int k0, int n0, int tid)
{
  __shared__ u16 tile[64][68];
  #pragma unroll
  for (int it = 0; it < 4; ++it){
    int ci = tid + it * 256;
    int kr = ci >> 4, nc = ci & 15;
    float4 f = *(const float4*)(W + (size_t)(k0 + kr) * N + n0 + nc * 4);
    tile[kr][nc*4+0] = f2bf(f.x);
    tile[kr][nc*4+1] = f2bf(f.y);
    tile[kr][nc*4+2] = f2bf(f.z);
    tile[kr][nc*4+3] = f2bf(f.w);
  }
  __syncthreads();
  #pragma unroll
  for (int it = 0; it < 4; ++it){
    int co = tid + it * 256;
    int nr = co >> 4, kc = co & 15;
    u16x4 o;
    o[0] = tile[kc*4+0][nr];
    o[1] = tile[kc*4+1][nr];
    o[2] = tile[kc*4+2][nr];
    o[3] = tile[kc*4+3][nr];
    *(u16x4*)(Wt + (size_t)(n0 + nr) * K + k0 + kc * 4) = o;
  }
}

// ---------------- fused 4x HxH weight transpose (Wq,Wk,Wv -> WqkvT; Wo -> WoT)
__global__ __launch_bounds__(256) void trans_qkvo_k(
    const float* __restrict__ Wq, const float* __restrict__ Wk,
    const float* __restrict__ Wv, const float* __restrict__ Wo,
    u16* __restrict__ WqkvT, u16* __restrict__ WoT)
{
  const int z = blockIdx.z;
  const float* src = (z == 0) ? Wq : (z == 1) ? Wk : (z == 2) ? Wv : Wo;
  u16* dst = (z == 3) ? WoT : (WqkvT + (size_t)z * 1024 * 1024);
  trans_tile(src, dst, H_, H_, blockIdx.y * 64, blockIdx.x * 64, threadIdx.x);
}

// ---------------- generic transpose (Wfc, Wpr)
__global__ __launch_bounds__(256) void transpose_cvt(const float* __restrict__ W,
                                                     u16* __restrict__ Wt, int K, int N)
{
  trans_tile(W, Wt, K, N, blockIdx.y * 64, blockIdx.x * 64, threadIdx.x);
}

// ---------------- per-head V transpose: vtg[bh][d][t] = v[b,t,h,d]
__global__ __launch_bounds__(256) void vtrans_k(const u16* __restrict__ qkv,
                                                u16* __restrict__ vtg)
{
  __shared__ u16 tile[64][72];
  const int bh = blockIdx.y, tt = blockIdx.x * 64;
  const int b = bh >> 4, h = bh & 15;
  const size_t src = (size_t)b * T_ * QKV_S + h * HS_ + 2048;
  const int tid = threadIdx.x;
  #pragma unroll
  for (int it = 0; it < 2; ++it){
    int ci = tid + it * 256;
    int r = ci >> 3, c = ci & 7;
    bf16x8 vvv = *(const bf16x8*)(qkv + src + (size_t)(tt + r) * QKV_S + c * 8);
    *(bf16x8*)&tile[r][c * 8] = vvv;
  }
  __syncthreads();
  #pragma unroll
  for (int it = 0; it < 2; ++it){
    int co = tid + it * 256;
    int d = co >> 3, c = co & 7;
    bf16x8 ov;
    #pragma unroll
    for (int j = 0; j < 8; ++j) ov[j] = (short)tile[c * 8 + j][d];
    *(bf16x8*)(vtg + (size_t)bh * HS_ * T_ + (size_t)d * T_ + tt + c * 8) = ov;
  }
}

// ---------------- small prep: bias concat (3072) + rope cos/sin table (32768)
__global__ void prep_small_k(const float* __restrict__ a, const float* __restrict__ b,
                             const float* __restrict__ c, float* __restrict__ o,
                             float* __restrict__ tab){
  int i = blockIdx.x * 256 + threadIdx.x;
  if (i < QKV_S){
    o[i] = (i < 1024) ? a[i] : (i < 2048) ? b[i - 1024] : c[i - 2048];
  } else {
    int j = i - QKV_S;
    if (j < T_ * 32){
      int t = j >> 5, f = j & 31;
      float inv = powf(10000.0f, -(float)f * (1.0f / 32.0f));
      float ang = (float)t * inv;
      tab[j*2+0] = cosf(ang);
      tab[j*2+1] = sinf(ang);
    }
  }
}

// ---------------- LayerNorm: fp32 in -> bf16 out, one row (1024) per block
__global__ __launch_bounds__(256) void ln_kernel(const float* __restrict__ x,
    const float* __restrict__ w, const float* __restrict__ bgain,
    u16* __restrict__ out)
{
  const int row = blockIdx.x;
  const int t = threadIdx.x;
  float4 vv = ((const float4*)(x + (size_t)row * H_))[t];
  float s  = vv.x + vv.y + vv.z + vv.w;
  float s2 = vv.x*vv.x + vv.y*vv.y + vv.z*vv.z + vv.w*vv.w;
  #pragma unroll
  for (int mm = 1; mm < 64; mm <<= 1){ s += __shfl_xor(s, mm); s2 += __shfl_xor(s2, mm); }
  __shared__ float red[8];
  int wid = t >> 6;
  if ((t & 63) == 0){ red[wid] = s; red[4 + wid] = s2; }
  __syncthreads();
  s  = red[0] + red[1] + red[2] + red[3];
  s2 = red[4] + red[5] + red[6] + red[7];
  float mu  = s * (1.0f / H_);
  float var = s2 * (1.0f / H_) - mu * mu;
  float rin = rsqrtf(var + 1e-5f);
  float4 wv = ((const float4*)w)[t];
  float4 bv = ((const float4*)bgain)[t];
  u16x4 ov;
  ov[0] = f2bf((vv.x - mu) * rin * wv.x + bv.x);
  ov[1] = f2bf((vv.y - mu) * rin * wv.y + bv.y);
  ov[2] = f2bf((vv.z - mu) * rin * wv.z + bv.z);
  ov[3] = f2bf((vv.w - mu) * rin * wv.w + bv.w);
  ((u16x4*)(out + (size_t)row * H_))[t] = ov;
}

// ---------------- GEMM 8-phase (BM=BN=256, BK=64): T3+T4 schedule.
// 8 waves (2m x 4n), wave tile 128x64 (acc 8x4), swapped operands.
// LDS: 2 buffers x {A,B} x 2 K-halves x [256 rows][4 chunks][8 u16] = 128KB.
// Per K-tile: 4 phases, each {ds-read subtile | stage 1 half-tile -> barrier
// -> lgkmcnt(0) -> setprio(1) 16 MFMA setprio(0) -> barrier}; counted
// vmcnt(4) ONLY at end of phases 1 and 3 (never 0 in steady state).
// EPI 0: bf16. EPI 1: bf16 gelu. EPI 2: bf16 + fused RoPE (cols<2048).
template<int EPI>
__global__ __launch_bounds__(512, 1) void gemm8p_kernel(
    const u16* __restrict__ A, const u16* __restrict__ Bt,
    const float* __restrict__ bias, const float* __restrict__ rtab,
    void* __restrict__ Cout, int M, int N, int K)
{
  __shared__ __attribute__((aligned(16))) u16 Abuf[2][2][8192];
  __shared__ __attribute__((aligned(16))) u16 Bbuf[2][2][8192];
  const int tid  = threadIdx.x;
  const int lane = tid & 63;
  const int wid  = tid >> 6;           // 0..7
  const int wm = wid >> 2, wn = wid & 3;
  const int lrow = lane & 15, lkg = lane >> 4;

  // XCD-aware bijective swizzle (nwg % 8 == 0)
  const int gx  = gridDim.x;
  const int nwg = gx * gridDim.y;
  const int wg  = blockIdx.y * gx + blockIdx.x;
  const int nx  = nwg >> 3;
  const int swz = (wg & 7) * nx + (wg >> 3);
  const int m0 = (swz / gx) * 256, n0 = (swz % gx) * 256;

  // staging: half-tile = one operand, one 32-col K-half = 1024 chunks;
  // thread covers chunk ci=tid (row r0) and ci=tid+512 (row r0+128).
  const int r0 = tid >> 2, c0 = tid & 3;
  const int sc = c0 ^ ((r0 >> 1) & 3);          // invariant under r0+128
  const u16* As0 = A  + (size_t)(m0 + r0) * K + sc * 8;
  const u16* As1 = As0 + (size_t)128 * K;
  const u16* Bs0 = Bt + (size_t)(n0 + r0) * K + sc * 8;
  const u16* Bs1 = Bs0 + (size_t)128 * K;
  const int dlo = tid * 8, dhi = (tid + 512) * 8;

  // loop-invariant frag byte offsets (within one K-half region)
  int aoff[8], boff[4];
  #pragma unroll
  for (int mi = 0; mi < 8; ++mi){
    int r = wm*128 + mi*16 + lrow;
    aoff[mi] = (r*4 + (lkg ^ ((r >> 1) & 3))) * 16;
  }
  #pragma unroll
  for (int ni = 0; ni < 4; ++ni){
    int r = wn*64 + ni*16 + lrow;
    boff[ni] = (r*4 + (lkg ^ ((r >> 1) & 3))) * 16;
  }

  f32x4 acc[8][4] = {};
  const int NT = K >> 6;   // 64-col K-tiles

  // prologue: stage tile0 in order Ak0, Bk0, Ak1, Bk1 (8 loads)
  gload_lds16(As0,      &Abuf[0][0][dlo]); gload_lds16(As1,      &Abuf[0][0][dhi]);
  gload_lds16(Bs0,      &Bbuf[0][0][dlo]); gload_lds16(Bs1,      &Bbuf[0][0][dhi]);
  gload_lds16(As0 + 32, &Abuf[0][1][dlo]); gload_lds16(As1 + 32, &Abuf[0][1][dhi]);
  gload_lds16(Bs0 + 32, &Bbuf[0][1][dlo]); gload_lds16(Bs1 + 32, &Bbuf[0][1][dhi]);
  asm volatile("s_waitcnt vmcnt(4)" ::: "memory");   // Ak0,Bk0 landed
  __builtin_amdgcn_s_barrier();

  for (int t = 0; t < NT; ++t){
    const int cb = t & 1, nb = (t + 1) & 1;
    const int koff = (t + 1) << 6;
    const char* Ak0 = (const char*)&Abuf[cb][0][0];
    const char* Ak1 = (const char*)&Abuf[cb][1][0];
    const char* Bk0 = (const char*)&Bbuf[cb][0][0];
    const char* Bk1 = (const char*)&Bbuf[cb][1][0];
    const bool pre = (t + 1 < NT);
    bf16x8 af[8], bf[4];

    // ---- phase 0: ds-read af(k0)+bf01(k0) | stage T+1.Ak0
    #pragma unroll
    for (int mi = 0; mi < 8; ++mi) af[mi] = *(const bf16x8*)(Ak0 + aoff[mi]);
    bf[0] = *(const bf16x8*)(Bk0 + boff[0]);
    bf[1] = *(const bf16x8*)(Bk0 + boff[1]);
    if (pre){ gload_lds16(As0 + koff, &Abuf[nb][0][dlo]);
              gload_lds16(As1 + koff, &Abuf[nb][0][dhi]); }
    __builtin_amdgcn_s_barrier();
    asm volatile("s_waitcnt lgkmcnt(0)" ::: "memory");
    __builtin_amdgcn_sched_barrier(0);
    __builtin_amdgcn_s_setprio(1);
    #pragma unroll
    for (int mi = 0; mi < 8; ++mi){
      acc[mi][0] = __builtin_amdgcn_mfma_f32_16x16x32_bf16(bf[0], af[mi], acc[mi][0], 0, 0, 0);
      acc[mi][1] = __builtin_amdgcn_mfma_f32_16x16x32_bf16(bf[1], af[mi], acc[mi][1], 0, 0, 0);
    }
    __builtin_amdgcn_s_setprio(0);
    __builtin_amdgcn_s_barrier();

    // ---- phase 1: ds-read bf23(k0) | stage T+1.Bk0 | vmcnt(4) at end
    bf[2] = *(const bf16x8*)(Bk0 + boff[2]);
    bf[3] = *(const bf16x8*)(Bk0 + boff[3]);
    if (pre){ gload_lds16(Bs0 + koff, &Bbuf[nb][0][dlo]);
              gload_lds16(Bs1 + koff, &Bbuf[nb][0][dhi]); }
    __builtin_amdgcn_s_barrier();
    asm volatile("s_waitcnt lgkmcnt(0)" ::: "memory");
    __builtin_amdgcn_sched_barrier(0);
    __builtin_amdgcn_s_setprio(1);
    #pragma unroll
    for (int mi = 0; mi < 8; ++mi){
      acc[mi][2] = __builtin_amdgcn_mfma_f32_16x16x32_bf16(bf[2], af[mi], acc[mi][2], 0, 0, 0);
      acc[mi][3] = __builtin_amdgcn_mfma_f32_16x16x32_bf16(bf[3], af[mi], acc[mi][3], 0, 0, 0);
    }
    __builtin_amdgcn_s_setprio(0);
    if (pre) asm volatile("s_waitcnt vmcnt(4)" ::: "memory");   // T.Ak1,T.Bk1 landed
    else     asm volatile("s_waitcnt vmcnt(0)" ::: "memory");
    __builtin_amdgcn_s_barrier();

    // ---- phase 2: ds-read af(k1)+bf01(k1) | stage T+1.Ak1
    #pragma unroll
    for (int mi = 0; mi < 8; ++mi) af[mi] = *(const bf16x8*)(Ak1 + aoff[mi]);
    bf[0] = *(const bf16x8*)(Bk1 + boff[0]);
    bf[1] = *(const bf16x8*)(Bk1 + boff[1]);
    if (pre){ gload_lds16(As0 + koff + 32, &Abuf[nb][1][dlo]);
              gload_lds16(As1 + koff + 32, &Abuf[nb][1][dhi]); }
    __builtin_amdgcn_s_barrier();
    asm volatile("s_waitcnt lgkmcnt(0)" ::: "memory");
    __builtin_amdgcn_sched_barrier(0);
    __builtin_amdgcn_s_setprio(1);
    #pragma unroll
    for (int mi = 0; mi < 8; ++mi){
      acc[mi][0] = __builtin_amdgcn_mfma_f32_16x16x32_bf16(bf[0], af[mi], acc[mi][0], 0, 0, 0);
      acc[mi][1] = __builtin_amdgcn_mfma_f32_16x16x32_bf16(bf[1], af[mi], acc[mi][1], 0, 0, 0);
    }
    __builtin_amdgcn_s_setprio(0);
    __builtin_amdgcn_s_barrier();

    // ---- phase 3: ds-read bf23(k1) | stage T+1.Bk1 | vmcnt(4) at end
    bf[2] = *(const bf16x8*)(Bk1 + boff[2]);
    bf[3] = *(const bf16x8*)(Bk1 + boff[3]);
    if (pre){ gload_lds16(Bs0 + koff + 32, &Bbuf[nb][1][dlo]);
              gload_lds16(Bs1 + koff + 32, &Bbuf[nb][1][dhi]); }
    __builtin_amdgcn_s_barrier();
    asm volatile("s_waitcnt lgkmcnt(0)" ::: "memory");
    __builtin_amdgcn_sched_barrier(0);
    __builtin_amdgcn_s_setprio(1);
    #pragma unroll
    for (int mi = 0; mi < 8; ++mi){
      acc[mi][2] = __builtin_amdgcn_mfma_f32_16x16x32_bf16(bf[2], af[mi], acc[mi][2], 0, 0, 0);
      acc[mi][3] = __builtin_amdgcn_mfma_f32_16x16x32_bf16(bf[3], af[mi], acc[mi][3], 0, 0, 0);
    }
    __builtin_amdgcn_s_setprio(0);
    if (pre) asm volatile("s_waitcnt vmcnt(4)" ::: "memory");   // T+1.Ak0,Bk0 landed
    __builtin_amdgcn_s_barrier();
  }

  // epilogue: lane owns row = ...+lrow, cols = ...+lkg*4+0..3 (vectorized)
  #pragma unroll
  for (int mi = 0; mi < 8; ++mi){
    int row = m0 + wm*128 + mi*16 + lrow;
    #pragma unroll
    for (int ni = 0; ni < 4; ++ni){
      int col0 = n0 + wn*64 + ni*16 + lkg*4;
      float4 bv = *(const float4*)(bias + col0);
      float v0 = acc[mi][ni][0] + bv.x;
      float v1 = acc[mi][ni][1] + bv.y;
      float v2 = acc[mi][ni][2] + bv.z;
      float v3 = acc[mi][ni][3] + bv.w;
      if (EPI == 1){
        float u0 = 0.7978845608f * v0 + 0.0356774081f * v0 * v0 * v0;
        float u1 = 0.7978845608f * v1 + 0.0356774081f * v1 * v1 * v1;
        float u2 = 0.7978845608f * v2 + 0.0356774081f * v2 * v2 * v2;
        float u3 = 0.7978845608f * v3 + 0.0356774081f * v3 * v3 * v3;
        float e0 = exp2f(u0 * 2.8853900818f);
        float e1 = exp2f(u1 * 2.8853900818f);
        float e2 = exp2f(u2 * 2.8853900818f);
        float e3 = exp2f(u3 * 2.8853900818f);
        v0 = v0 - v0 / (e0 + 1.0f);
        v1 = v1 - v1 / (e1 + 1.0f);
        v2 = v2 - v2 / (e2 + 1.0f);
        v3 = v3 - v3 / (e3 + 1.0f);
      }
      if (EPI == 2){
        if (col0 < 2048){
          int tt = row & (T_ - 1);
          const float* rt = rtab + ((size_t)tt * 32 + ((col0 & 63) >> 1)) * 2;
          float cc0 = rt[0], ss0 = rt[1], cc1 = rt[2], ss1 = rt[3];
          float q0 = v0 * cc0 - v1 * ss0, q1 = v0 * ss0 + v1 * cc0;
          float q2 = v2 * cc1 - v3 * ss1, q3 = v2 * ss1 + v3 * cc1;
          if (col0 < 1024){
            const float qs = 0.125f * 1.44269504f;
            q0 *= qs; q1 *= qs; q2 *= qs; q3 *= qs;
          }
          v0 = q0; v1 = q1; v2 = q2; v3 = q3;
        }
      }
      uint2 ov;
      ov.x = pack2bf(v0, v1);
      ov.y = pack2bf(v2, v3);
      *(uint2*)((u16*)Cout + (size_t)row * N + col0) = ov;
    }
  }
}

// ---------------- GEMM (BM=64, BN=128): skinny-N GEMMs (Wo, Wpr) — round 13.
// 256 thr = 4 waves (2m x 2n), wave tile 32x64, swapped operands,
// RING=4, counted vmcnt, fp32 + bias + residual output.
template<int RING>
__global__ __launch_bounds__(256, 2) void gemm64_kernel(
    const u16* __restrict__ A, const u16* __restrict__ Bt,
    const float* __restrict__ bias, const float* __restrict__ res,
    float* __restrict__ Cout, int M, int N, int K)
{
  __shared__ __attribute__((aligned(16))) u16 As[RING][64 * 32];
  __shared__ __attribute__((aligned(16))) u16 Bs[RING][128 * 32];
  const int tid  = threadIdx.x;
  const int lane = tid & 63;
  const int wid  = tid >> 6;           // 0..3
  const int wm = wid >> 1, wn = wid & 1;
  const int lrow = lane & 15, lkg = lane >> 4;

  const int gx  = gridDim.x;           // N/128
  const int nwg = gx * gridDim.y;
  const int wg  = blockIdx.y * gx + blockIdx.x;
  const int nx  = nwg >> 3;
  const int swz = (wg & 7) * nx + (wg >> 3);
  const int m0 = (swz / gx) * 64, n0 = (swz % gx) * 128;

  const int srow = tid >> 2;           // 0..63
  const int sdc  = tid & 3;
  const int scs  = sdc ^ ((srow >> 1) & 3);
  const u16* Asrc  = A  + (size_t)(m0 + srow) * K + scs * 8;
  const u16* Bsrc0 = Bt + (size_t)(n0 + srow) * K + scs * 8;
  const u16* Bsrc1 = Bsrc0 + (size_t)64 * K;
  const int dA  = (srow * 4 + sdc) * 8;
  const int dB1 = dA + 64 * 32;

  int aoff[2], boff[4];
  #pragma unroll
  for (int mi = 0; mi < 2; ++mi){
    int r = wm*32 + mi*16 + lrow;
    aoff[mi] = (r*4 + (lkg ^ ((r >> 1) & 3))) * 16;
  }
  #pragma unroll
  for (int ni = 0; ni < 4; ++ni){
    int r = wn*64 + ni*16 + lrow;
    boff[ni] = (r*4 + (lkg ^ ((r >> 1) & 3))) * 16;
  }

  f32x4 acc[2][4] = {};
  const int NT = K >> 5;
  constexpr int DIST = RING - 1;

  #pragma unroll
  for (int s = 0; s < DIST; ++s){
    gload_lds16(Asrc  + (s << 5), &As[s][dA]);
    gload_lds16(Bsrc0 + (s << 5), &Bs[s][dA]);
    gload_lds16(Bsrc1 + (s << 5), &Bs[s][dB1]);
  }

  int rs = 0, wsl = DIST;
  for (int t = 0; t < NT; ++t){
    int cnt = NT - 1 - t; if (cnt > DIST - 1) cnt = DIST - 1;
    if (cnt >= 2)      asm volatile("s_waitcnt vmcnt(6)" ::: "memory");
    else if (cnt == 1) asm volatile("s_waitcnt vmcnt(3)" ::: "memory");
    else               asm volatile("s_waitcnt vmcnt(0)" ::: "memory");
    __builtin_amdgcn_s_barrier();

    const char* Ab = (const char*)&As[rs][0];
    const char* Bb = (const char*)&Bs[rs][0];
    rs = (rs + 1 == RING) ? 0 : rs + 1;

    bf16x8 af[2], bfr[4];
    #pragma unroll
    for (int mi = 0; mi < 2; ++mi)
      af[mi] = *(const bf16x8*)(Ab + aoff[mi]);
    #pragma unroll
    for (int ni = 0; ni < 4; ++ni)
      bfr[ni] = *(const bf16x8*)(Bb + boff[ni]);
    __builtin_amdgcn_sched_barrier(0);

    if (t + DIST < NT){
      int k0 = (t + DIST) << 5;
      gload_lds16(Asrc  + k0, &As[wsl][dA]);
      gload_lds16(Bsrc0 + k0, &Bs[wsl][dA]);
      gload_lds16(Bsrc1 + k0, &Bs[wsl][dB1]);
    }
    wsl = (wsl + 1 == RING) ? 0 : wsl + 1;

    #pragma unroll
    for (int mi = 0; mi < 2; ++mi)
      #pragma unroll
      for (int ni = 0; ni < 4; ++ni)
        acc[mi][ni] = __builtin_amdgcn_mfma_f32_16x16x32_bf16(bfr[ni], af[mi], acc[mi][ni], 0, 0, 0);
  }

  #pragma unroll
  for (int mi = 0; mi < 2; ++mi){
    int row = m0 + wm*32 + mi*16 + lrow;
    #pragma unroll
    for (int ni = 0; ni < 4; ++ni){
      int col0 = n0 + wn*64 + ni*16 + lkg*4;
      float4 bv = *(const float4*)(bias + col0);
      float4 rv = *(const float4*)(res + (size_t)row * N + col0);
      float4 ov;
      ov.x = acc[mi][ni][0] + bv.x + rv.x;
      ov.y = acc[mi][ni][1] + bv.y + rv.y;
      ov.z = acc[mi][ni][2] + bv.z + rv.z;
      ov.w = acc[mi][ni][3] + bv.w + rv.w;
      *(float4*)(Cout + (size_t)row * N + col0) = ov;
    }
  }
}

// ---------------- fused attention (swapped-operand form), 8 waves / 128 q-rows
__global__ __launch_bounds__(512, 4) void attn_kernel(
    const u16* __restrict__ qkv, const u16* __restrict__ vtg,
    u16* __restrict__ out)
{
  __shared__ u16 K_lds[3][64 * 64];
  __shared__ u16 VT_lds[3][64 * 64];
  __shared__ u16 P_lds[8][16 * 64];
  const int tid = threadIdx.x, lane = tid & 63, w = tid >> 6;   // w: 0..7
  const int lrow = lane & 15, lkg = lane >> 4;
  const int q0 = blockIdx.x * 128;
  const int bh = blockIdx.y, b = bh >> 4, h = bh & 15;
  const size_t baseq  = (size_t)b * T_ * QKV_S + h * HS_;
  const size_t basek  = baseq + 1024;
  const size_t basevt = (size_t)bh * HS_ * T_;
  const size_t baseo  = (size_t)b * T_ * H_ + h * HS_;
  const int qg = q0 + w * 16 + lrow;      // this lane's q row

  bf16x8 qa[2];
  {
    const u16* qp = qkv + baseq + (size_t)qg * QKV_S + lkg * 8;
    qa[0] = *(const bf16x8*)qp;
    qa[1] = *(const bf16x8*)(qp + 32);
  }

  const int r0 = tid >> 3, c0 = tid & 7, g0 = c0 ^ (r0 & 7);
  const u16* kap = qkv + basek + (size_t)r0 * QKV_S + g0 * 8;
  const u16* vap = vtg + basevt + (size_t)r0 * T_ + g0 * 8;
  const int kd = tid * 8;

  f32x4 o[4] = {};
  float mrun = -1e30f, lrun = 0.f;

  #pragma unroll
  for (int s = 0; s < 2; ++s){
    gload_lds16(kap + (size_t)s * 64 * QKV_S, &K_lds[s][kd]);
    gload_lds16(vap + s * 64,                 &VT_lds[s][kd]);
  }

  int rs = 0, wsl = 2;
  for (int t = 0; t < 16; ++t){
    const int kt = t << 6;
    if (t < 15) asm volatile("s_waitcnt vmcnt(2)" ::: "memory");
    else        asm volatile("s_waitcnt vmcnt(0)" ::: "memory");
    __builtin_amdgcn_s_barrier();
    __builtin_amdgcn_sched_barrier(0);

    if (t + 2 < 16){
      gload_lds16(kap + (size_t)(t + 2) * 64 * QKV_S, &K_lds[wsl][kd]);
      gload_lds16(vap + (t + 2) * 64,                 &VT_lds[wsl][kd]);
    }
    wsl = (wsl + 1 == 3) ? 0 : wsl + 1;

    const u16* Kc  = K_lds[rs];
    const u16* VTc = VT_lds[rs];
    rs = (rs + 1 == 3) ? 0 : rs + 1;

    f32x4 s[4];
    __builtin_amdgcn_s_setprio(1);
    #pragma unroll
    for (int mi = 0; mi < 4; ++mi){
      f32x4 c = {};
      #pragma unroll
      for (int ss = 0; ss < 2; ++ss){
        int r = mi * 16 + lrow;
        int off = r * 128 + (((ss * 4 + lkg) ^ (r & 7)) * 16);
        bf16x8 kb = *(const bf16x8*)((const char*)Kc + off);
        c = __builtin_amdgcn_mfma_f32_16x16x32_bf16(kb, qa[ss], c, 0, 0, 0);
      }
      s[mi] = c;
    }
    __builtin_amdgcn_s_setprio(0);

    float mt = fmaxf(fmaxf(fmaxf(s[0][0], s[0][1]), fmaxf(s[0][2], s[0][3])),
                     fmaxf(fmaxf(s[1][0], s[1][1]), fmaxf(s[1][2], s[1][3])));
    mt = fmaxf(mt, fmaxf(fmaxf(fmaxf(s[2][0], s[2][1]), fmaxf(s[2][2], s[2][3])),
                         fmaxf(fmaxf(s[3][0], s[3][1]), fmaxf(s[3][2], s[3][3]))));
    mt = fmaxf(mt, __shfl_xor(mt, 16));
    mt = fmaxf(mt, __shfl_xor(mt, 32));
    if (!__all(mt <= mrun + 8.f)){       // defer-max
      float mnew = fmaxf(mrun, mt);
      float fsc = exp2f(mrun - mnew);
      lrun *= fsc;
      #pragma unroll
      for (int nf = 0; nf < 4; ++nf){
        #pragma unroll
        for (int r = 0; r < 4; ++r) o[nf][r] *= fsc;
      }
      mrun = mnew;
    }

    float p[16];
    float ls = 0.f;
    #pragma unroll
    for (int mi = 0; mi < 4; ++mi){
      #pragma unroll
      for (int r = 0; r < 4; ++r){
        int key = kt + mi * 16 + lkg * 4 + r;
        float pv = exp2f(s[mi][r] - mrun);
        ls += pv;                          // denominator over ALL keys
        p[mi * 4 + r] = (key <= qg) ? pv : 0.f;
      }
    }
    ls += __shfl_xor(ls, 16);
    ls += __shfl_xor(ls, 32);
    lrun += ls;

    if (kt <= q0 + w * 16 + 15){
      char* pbase = (char*)&P_lds[w][0];
      const int rx = (lrow & 7) << 4;
      #pragma unroll
      for (int mi = 0; mi < 4; ++mi){
        uint2 pk;
        pk.x = pack2bf(p[mi*4+0], p[mi*4+1]);
        pk.y = pack2bf(p[mi*4+2], p[mi*4+3]);
        *(uint2*)(pbase + (lrow * 128 + ((mi * 32 + lkg * 8) ^ rx))) = pk;
      }
      __builtin_amdgcn_s_setprio(1);
      #pragma unroll
      for (int ss = 0; ss < 2; ++ss){
        bf16x8 pb = *(const bf16x8*)(pbase + (lrow * 128 + ((ss * 64 + lkg * 16) ^ rx)));
        #pragma unroll
        for (int nfd = 0; nfd < 4; ++nfd){
          int d = nfd * 16 + lrow;
          int off = d * 128 + (((ss * 4 + lkg) ^ (d & 7)) * 16);
          bf16x8 vb = *(const bf16x8*)((const char*)VTc + off);
          o[nfd] = __builtin_amdgcn_mfma_f32_16x16x32_bf16(vb, pb, o[nfd], 0, 0, 0);
        }
      }
      __builtin_amdgcn_s_setprio(0);
    }
  }

  float rl = 1.0f / lrun;
  #pragma unroll
  for (int nfd = 0; nfd < 4; ++nfd){
    uint2 ov;
    ov.x = pack2bf(o[nfd][0] * rl, o[nfd][1] * rl);
    ov.y = pack2bf(o[nfd][2] * rl, o[nfd][3] * rl);
    *(uint2*)(out + baseo + (size_t)qg * H_ + nfd * 16 + lkg * 4) = ov;
  }
}

extern "C" void kernel_launch(void* const* d_in, const int* in_sizes, int n_in,
                              void* d_out, int out_size, void* d_ws, size_t ws_size,
                              hipStream_t stream)
{
  (void)in_sizes; (void)n_in; (void)out_size; (void)ws_size;
  const float* x    = (const float*)d_in[0];
  const float* Wq   = (const float*)d_in[1];
  const float* bq   = (const float*)d_in[2];
  const float* Wk   = (const float*)d_in[3];
  const float* bk   = (const float*)d_in[4];
  const float* Wv   = (const float*)d_in[5];
  const float* bv   = (const float*)d_in[6];
  const float* Wo   = (const float*)d_in[7];
  const float* bo   = (const float*)d_in[8];
  const float* ln1w = (const float*)d_in[9];
  const float* ln1b = (const float*)d_in[10];
  const float* ln2w = (const float*)d_in[11];
  const float* ln2b = (const float*)d_in[12];
  const float* Wfc  = (const float*)d_in[13];
  const float* bfc  = (const float*)d_in[14];
  const float* Wpr  = (const float*)d_in[15];
  const float* bpr  = (const float*)d_in[16];

  char* ws = (char*)d_ws;
  u16*  WqkvT = (u16*)(ws + ((size_t) 0 << 20));   //  6MB [3072][1024]
  u16*  WoT   = (u16*)(ws + ((size_t) 6 << 20));   //  2MB
  u16*  WfcT  = (u16*)(ws + ((size_t) 8 << 20));   //  8MB [FF][H]
  u16*  WprT  = (u16*)(ws + ((size_t)16 << 20));   //  8MB [H][FF]
  u16*  h1    = (u16*)(ws + ((size_t)24 << 20));   //  8MB; reused as attnout
  u16*  qkvb  = (u16*)(ws + ((size_t)32 << 20));   // 24MB [M][3072]; dead after attn
  float* x1   = (float*)(ws + ((size_t)32 << 20)); // 16MB (reuses qkvb region)
  u16*  h2    = (u16*)(ws + ((size_t)48 << 20));   //  8MB (reuses qkvb region)
  float* bqkv = (float*)(ws + ((size_t)56 << 20)); // 12KB (dead before mb written)
  float* rtab = (float*)(ws + ((size_t)56 << 20) + (64 << 10)); // 256KB (dead before mb)
  u16*  vtg   = (u16*)(ws + ((size_t)57 << 20));   //  8MB (dead before mb)
  u16*  mb    = (u16*)(ws + ((size_t)56 << 20));   // 32MB (overwrites bqkv/rtab/vtg)
  u16*  attnout = h1;

  dim3 blk(256);
  dim3 gblk(512);

  // weights: transpose + bf16 (QKV concatenated; 4 HxH in one launch)
  trans_qkvo_k<<<dim3(H_/64, H_/64, 4), blk, 0, stream>>>(Wq, Wk, Wv, Wo, WqkvT, WoT);
  transpose_cvt<<<dim3(FF_/64, H_/64),  blk, 0, stream>>>(Wfc, WfcT, H_,  FF_);
  transpose_cvt<<<dim3(H_/64,  FF_/64), blk, 0, stream>>>(Wpr, WprT, FF_, H_);
  prep_small_k<<<dim3((QKV_S + T_*32 + 255)/256), blk, 0, stream>>>(bq, bk, bv, bqkv, rtab);

  // LN1
  ln_kernel<<<dim3(M_), blk, 0, stream>>>(x, ln1w, ln1b, h1);
  // fused QKV projection + RoPE — 8-phase 256x256, grid 12x16
  gemm8p_kernel<2><<<dim3(QKV_S/256, M_/256), gblk, 0, stream>>>(h1, WqkvT, bqkv, rtab, qkvb, M_, QKV_S, H_);
  // per-head V transpose
  vtrans_k<<<dim3(T_/64, B_*NH_), blk, 0, stream>>>(qkvb, vtg);
  // attention — 8 waves, 128 q-rows/block
  attn_kernel<<<dim3(T_/128, B_*NH_), dim3(512), 0, stream>>>(qkvb, vtg, attnout);
  // out projection + residual -> x1 (fp32) — BM=64 grid 8x64 (2 blk/CU)
  gemm64_kernel<4><<<dim3(H_/128, M_/64), blk, 0, stream>>>(attnout, WoT, bo, x, x1, M_, H_, H_);
  // LN2
  ln_kernel<<<dim3(M_), blk, 0, stream>>>(x1, ln2w, ln2b, h2);
  // MLP — Wfc 8-phase 256x256 grid 16x16; Wpr BM=64 grid 8x64
  gemm8p_kernel<1><<<dim3(FF_/256, M_/256), gblk, 0, stream>>>(h2, WfcT, bfc, nullptr, mb, M_, FF_, H_);
  gemm64_kernel<4><<<dim3(H_/128, M_/64), blk, 0, stream>>>(mb, WprT, bpr, x1, (float*)d_out, M_, H_, FF_);
}

// Round 17
// 239.130 us; speedup vs baseline: 1.1196x; 1.0472x over previous
//
#include <hip/hip_runtime.h>
#include <hip/hip_bf16.h>

typedef unsigned short u16;
typedef __attribute__((ext_vector_type(8))) short bf16x8;
typedef __attribute__((ext_vector_type(4))) float f32x4;
typedef __attribute__((ext_vector_type(4))) unsigned short u16x4;

#define B_  4
#define T_  1024
#define H_  1024
#define NH_ 16
#define HS_ 64
#define FF_ 4096
#define M_  (B_*T_)
#define QKV_S 3072

__device__ __forceinline__ u16 f2bf(float f){
  union { float f; unsigned u; } v; v.f = f;
  unsigned r = v.u + 0x7fffu + ((v.u >> 16) & 1u);
  return (u16)(r >> 16);
}
__device__ __forceinline__ float bf2f(u16 h){
  union { unsigned u; float f; } v; v.u = ((unsigned)h) << 16;
  return v.f;
}
__device__ __forceinline__ unsigned pack2bf(float a, float b){
  __hip_bfloat162 h = __float22bfloat162_rn(make_float2(a, b));
  union { __hip_bfloat162 h; unsigned u; } c; c.h = h;
  return c.u;
}

__device__ __forceinline__ void gload_lds16(const void* g, void* l){
  __builtin_amdgcn_global_load_lds(
      (const __attribute__((address_space(1))) unsigned int*)g,
      (__attribute__((address_space(3))) unsigned int*)l,
      16, 0, 0);
}

// ---------------- 64x64 transpose tile body (fp32 -> bf16)
__device__ __forceinline__ void trans_tile(const float* __restrict__ W,
                                           u16* __restrict__ Wt, int K, int N,
                                           int k0, int n0, int tid)
{
  __shared__ u16 tile[64][68];
  #pragma unroll
  for (int it = 0; it < 4; ++it){
    int ci = tid + it * 256;
    int kr = ci >> 4, nc = ci & 15;
    float4 f = *(const float4*)(W + (size_t)(k0 + kr) * N + n0 + nc * 4);
    tile[kr][nc*4+0] = f2bf(f.x);
    tile[kr][nc*4+1] = f2bf(f.y);
    tile[kr][nc*4+2] = f2bf(f.z);
    tile[kr][nc*4+3] = f2bf(f.w);
  }
  __syncthreads();
  #pragma unroll
  for (int it = 0; it < 4; ++it){
    int co = tid + it * 256;
    int nr = co >> 4, kc = co & 15;
    u16x4 o;
    o[0] = tile[kc*4+0][nr];
    o[1] = tile[kc*4+1][nr];
    o[2] = tile[kc*4+2][nr];
    o[3] = tile[kc*4+3][nr];
    *(u16x4*)(Wt + (size_t)(n0 + nr) * K + k0 + kc * 4) = o;
  }
}

// ---------------- fused 4x HxH weight transpose (Wq,Wk,Wv -> WqkvT; Wo -> WoT)
__global__ __launch_bounds__(256) void trans_qkvo_k(
    const float* __restrict__ Wq, const float* __restrict__ Wk,
    const float* __restrict__ Wv, const float* __restrict__ Wo,
    u16* __restrict__ WqkvT, u16* __restrict__ WoT)
{
  const int z = blockIdx.z;
  const float* src = (z == 0) ? Wq : (z == 1) ? Wk : (z == 2) ? Wv : Wo;
  u16* dst = (z == 3) ? WoT : (WqkvT + (size_t)z * 1024 * 1024);
  trans_tile(src, dst, H_, H_, blockIdx.y * 64, blockIdx.x * 64, threadIdx.x);
}

// ---------------- generic transpose (Wfc, Wpr)
__global__ __launch_bounds__(256) void transpose_cvt(const float* __restrict__ W,
                                                     u16* __restrict__ Wt, int K, int N)
{
  trans_tile(W, Wt, K, N, blockIdx.y * 64, blockIdx.x * 64, threadIdx.x);
}

// ---------------- per-head V transpose: vtg[bh][d][t] = v[b,t,h,d]
__global__ __launch_bounds__(256) void vtrans_k(const u16* __restrict__ qkv,
                                                u16* __restrict__ vtg)
{
  __shared__ u16 tile[64][72];
  const int bh = blockIdx.y, tt = blockIdx.x * 64;
  const int b = bh >> 4, h = bh & 15;
  const size_t src = (size_t)b * T_ * QKV_S + h * HS_ + 2048;
  const int tid = threadIdx.x;
  #pragma unroll
  for (int it = 0; it < 2; ++it){
    int ci = tid + it * 256;
    int r = ci >> 3, c = ci & 7;
    bf16x8 vvv = *(const bf16x8*)(qkv + src + (size_t)(tt + r) * QKV_S + c * 8);
    *(bf16x8*)&tile[r][c * 8] = vvv;
  }
  __syncthreads();
  #pragma unroll
  for (int it = 0; it < 2; ++it){
    int co = tid + it * 256;
    int d = co >> 3, c = co & 7;
    bf16x8 ov;
    #pragma unroll
    for (int j = 0; j < 8; ++j) ov[j] = (short)tile[c * 8 + j][d];
    *(bf16x8*)(vtg + (size_t)bh * HS_ * T_ + (size_t)d * T_ + tt + c * 8) = ov;
  }
}

// ---------------- small prep: bias concat (3072) + rope cos/sin table (32768)
__global__ void prep_small_k(const float* __restrict__ a, const float* __restrict__ b,
                             const float* __restrict__ c, float* __restrict__ o,
                             float* __restrict__ tab){
  int i = blockIdx.x * 256 + threadIdx.x;
  if (i < QKV_S){
    o[i] = (i < 1024) ? a[i] : (i < 2048) ? b[i - 1024] : c[i - 2048];
  } else {
    int j = i - QKV_S;
    if (j < T_ * 32){
      int t = j >> 5, f = j & 31;
      float inv = powf(10000.0f, -(float)f * (1.0f / 32.0f));
      float ang = (float)t * inv;
      tab[j*2+0] = cosf(ang);
      tab[j*2+1] = sinf(ang);
    }
  }
}

// ---------------- LayerNorm: fp32 in -> bf16 out, one row (1024) per block
__global__ __launch_bounds__(256) void ln_kernel(const float* __restrict__ x,
    const float* __restrict__ w, const float* __restrict__ bgain,
    u16* __restrict__ out)
{
  const int row = blockIdx.x;
  const int t = threadIdx.x;
  float4 vv = ((const float4*)(x + (size_t)row * H_))[t];
  float s  = vv.x + vv.y + vv.z + vv.w;
  float s2 = vv.x*vv.x + vv.y*vv.y + vv.z*vv.z + vv.w*vv.w;
  #pragma unroll
  for (int mm = 1; mm < 64; mm <<= 1){ s += __shfl_xor(s, mm); s2 += __shfl_xor(s2, mm); }
  __shared__ float red[8];
  int wid = t >> 6;
  if ((t & 63) == 0){ red[wid] = s; red[4 + wid] = s2; }
  __syncthreads();
  s  = red[0] + red[1] + red[2] + red[3];
  s2 = red[4] + red[5] + red[6] + red[7];
  float mu  = s * (1.0f / H_);
  float var = s2 * (1.0f / H_) - mu * mu;
  float rin = rsqrtf(var + 1e-5f);
  float4 wv = ((const float4*)w)[t];
  float4 bv = ((const float4*)bgain)[t];
  u16x4 ov;
  ov[0] = f2bf((vv.x - mu) * rin * wv.x + bv.x);
  ov[1] = f2bf((vv.y - mu) * rin * wv.y + bv.y);
  ov[2] = f2bf((vv.z - mu) * rin * wv.z + bv.z);
  ov[3] = f2bf((vv.w - mu) * rin * wv.w + bv.w);
  ((u16x4*)(out + (size_t)row * H_))[t] = ov;
}

// ---------------- GEMM 8-phase (BM=BN=256, BK=64): T3+T4 schedule (round 16).
// EPI 0: bf16. EPI 1: bf16 gelu. EPI 2: bf16 + fused RoPE (cols<2048).
template<int EPI>
__global__ __launch_bounds__(512, 1) void gemm8p_kernel(
    const u16* __restrict__ A, const u16* __restrict__ Bt,
    const float* __restrict__ bias, const float* __restrict__ rtab,
    void* __restrict__ Cout, int M, int N, int K)
{
  __shared__ __attribute__((aligned(16))) u16 Abuf[2][2][8192];
  __shared__ __attribute__((aligned(16))) u16 Bbuf[2][2][8192];
  const int tid  = threadIdx.x;
  const int lane = tid & 63;
  const int wid  = tid >> 6;           // 0..7
  const int wm = wid >> 2, wn = wid & 3;
  const int lrow = lane & 15, lkg = lane >> 4;

  const int gx  = gridDim.x;
  const int nwg = gx * gridDim.y;
  const int wg  = blockIdx.y * gx + blockIdx.x;
  const int nx  = nwg >> 3;
  const int swz = (wg & 7) * nx + (wg >> 3);
  const int m0 = (swz / gx) * 256, n0 = (swz % gx) * 256;

  const int r0 = tid >> 2, c0 = tid & 3;
  const int sc = c0 ^ ((r0 >> 1) & 3);
  const u16* As0 = A  + (size_t)(m0 + r0) * K + sc * 8;
  const u16* As1 = As0 + (size_t)128 * K;
  const u16* Bs0 = Bt + (size_t)(n0 + r0) * K + sc * 8;
  const u16* Bs1 = Bs0 + (size_t)128 * K;
  const int dlo = tid * 8, dhi = (tid + 512) * 8;

  int aoff[8], boff[4];
  #pragma unroll
  for (int mi = 0; mi < 8; ++mi){
    int r = wm*128 + mi*16 + lrow;
    aoff[mi] = (r*4 + (lkg ^ ((r >> 1) & 3))) * 16;
  }
  #pragma unroll
  for (int ni = 0; ni < 4; ++ni){
    int r = wn*64 + ni*16 + lrow;
    boff[ni] = (r*4 + (lkg ^ ((r >> 1) & 3))) * 16;
  }

  f32x4 acc[8][4] = {};
  const int NT = K >> 6;

  gload_lds16(As0,      &Abuf[0][0][dlo]); gload_lds16(As1,      &Abuf[0][0][dhi]);
  gload_lds16(Bs0,      &Bbuf[0][0][dlo]); gload_lds16(Bs1,      &Bbuf[0][0][dhi]);
  gload_lds16(As0 + 32, &Abuf[0][1][dlo]); gload_lds16(As1 + 32, &Abuf[0][1][dhi]);
  gload_lds16(Bs0 + 32, &Bbuf[0][1][dlo]); gload_lds16(Bs1 + 32, &Bbuf[0][1][dhi]);
  asm volatile("s_waitcnt vmcnt(4)" ::: "memory");
  __builtin_amdgcn_s_barrier();

  for (int t = 0; t < NT; ++t){
    const int cb = t & 1, nb = (t + 1) & 1;
    const int koff = (t + 1) << 6;
    const char* Ak0 = (const char*)&Abuf[cb][0][0];
    const char* Ak1 = (const char*)&Abuf[cb][1][0];
    const char* Bk0 = (const char*)&Bbuf[cb][0][0];
    const char* Bk1 = (const char*)&Bbuf[cb][1][0];
    const bool pre = (t + 1 < NT);
    bf16x8 af[8], bf[4];

    // ---- phase 0
    #pragma unroll
    for (int mi = 0; mi < 8; ++mi) af[mi] = *(const bf16x8*)(Ak0 + aoff[mi]);
    bf[0] = *(const bf16x8*)(Bk0 + boff[0]);
    bf[1] = *(const bf16x8*)(Bk0 + boff[1]);
    if (pre){ gload_lds16(As0 + koff, &Abuf[nb][0][dlo]);
              gload_lds16(As1 + koff, &Abuf[nb][0][dhi]); }
    __builtin_amdgcn_s_barrier();
    asm volatile("s_waitcnt lgkmcnt(0)" ::: "memory");
    __builtin_amdgcn_sched_barrier(0);
    __builtin_amdgcn_s_setprio(1);
    #pragma unroll
    for (int mi = 0; mi < 8; ++mi){
      acc[mi][0] = __builtin_amdgcn_mfma_f32_16x16x32_bf16(bf[0], af[mi], acc[mi][0], 0, 0, 0);
      acc[mi][1] = __builtin_amdgcn_mfma_f32_16x16x32_bf16(bf[1], af[mi], acc[mi][1], 0, 0, 0);
    }
    __builtin_amdgcn_s_setprio(0);
    __builtin_amdgcn_s_barrier();

    // ---- phase 1
    bf[2] = *(const bf16x8*)(Bk0 + boff[2]);
    bf[3] = *(const bf16x8*)(Bk0 + boff[3]);
    if (pre){ gload_lds16(Bs0 + koff, &Bbuf[nb][0][dlo]);
              gload_lds16(Bs1 + koff, &Bbuf[nb][0][dhi]); }
    __builtin_amdgcn_s_barrier();
    asm volatile("s_waitcnt lgkmcnt(0)" ::: "memory");
    __builtin_amdgcn_sched_barrier(0);
    __builtin_amdgcn_s_setprio(1);
    #pragma unroll
    for (int mi = 0; mi < 8; ++mi){
      acc[mi][2] = __builtin_amdgcn_mfma_f32_16x16x32_bf16(bf[2], af[mi], acc[mi][2], 0, 0, 0);
      acc[mi][3] = __builtin_amdgcn_mfma_f32_16x16x32_bf16(bf[3], af[mi], acc[mi][3], 0, 0, 0);
    }
    __builtin_amdgcn_s_setprio(0);
    if (pre) asm volatile("s_waitcnt vmcnt(4)" ::: "memory");
    else     asm volatile("s_waitcnt vmcnt(0)" ::: "memory");
    __builtin_amdgcn_s_barrier();

    // ---- phase 2
    #pragma unroll
    for (int mi = 0; mi < 8; ++mi) af[mi] = *(const bf16x8*)(Ak1 + aoff[mi]);
    bf[0] = *(const bf16x8*)(Bk1 + boff[0]);
    bf[1] = *(const bf16x8*)(Bk1 + boff[1]);
    if (pre){ gload_lds16(As0 + koff + 32, &Abuf[nb][1][dlo]);
              gload_lds16(As1 + koff + 32, &Abuf[nb][1][dhi]); }
    __builtin_amdgcn_s_barrier();
    asm volatile("s_waitcnt lgkmcnt(0)" ::: "memory");
    __builtin_amdgcn_sched_barrier(0);
    __builtin_amdgcn_s_setprio(1);
    #pragma unroll
    for (int mi = 0; mi < 8; ++mi){
      acc[mi][0] = __builtin_amdgcn_mfma_f32_16x16x32_bf16(bf[0], af[mi], acc[mi][0], 0, 0, 0);
      acc[mi][1] = __builtin_amdgcn_mfma_f32_16x16x32_bf16(bf[1], af[mi], acc[mi][1], 0, 0, 0);
    }
    __builtin_amdgcn_s_setprio(0);
    __builtin_amdgcn_s_barrier();

    // ---- phase 3
    bf[2] = *(const bf16x8*)(Bk1 + boff[2]);
    bf[3] = *(const bf16x8*)(Bk1 + boff[3]);
    if (pre){ gload_lds16(Bs0 + koff + 32, &Bbuf[nb][1][dlo]);
              gload_lds16(Bs1 + koff + 32, &Bbuf[nb][1][dhi]); }
    __builtin_amdgcn_s_barrier();
    asm volatile("s_waitcnt lgkmcnt(0)" ::: "memory");
    __builtin_amdgcn_sched_barrier(0);
    __builtin_amdgcn_s_setprio(1);
    #pragma unroll
    for (int mi = 0; mi < 8; ++mi){
      acc[mi][2] = __builtin_amdgcn_mfma_f32_16x16x32_bf16(bf[2], af[mi], acc[mi][2], 0, 0, 0);
      acc[mi][3] = __builtin_amdgcn_mfma_f32_16x16x32_bf16(bf[3], af[mi], acc[mi][3], 0, 0, 0);
    }
    __builtin_amdgcn_s_setprio(0);
    if (pre) asm volatile("s_waitcnt vmcnt(4)" ::: "memory");
    __builtin_amdgcn_s_barrier();
  }

  #pragma unroll
  for (int mi = 0; mi < 8; ++mi){
    int row = m0 + wm*128 + mi*16 + lrow;
    #pragma unroll
    for (int ni = 0; ni < 4; ++ni){
      int col0 = n0 + wn*64 + ni*16 + lkg*4;
      float4 bv = *(const float4*)(bias + col0);
      float v0 = acc[mi][ni][0] + bv.x;
      float v1 = acc[mi][ni][1] + bv.y;
      float v2 = acc[mi][ni][2] + bv.z;
      float v3 = acc[mi][ni][3] + bv.w;
      if (EPI == 1){
        float u0 = 0.7978845608f * v0 + 0.0356774081f * v0 * v0 * v0;
        float u1 = 0.7978845608f * v1 + 0.0356774081f * v1 * v1 * v1;
        float u2 = 0.7978845608f * v2 + 0.0356774081f * v2 * v2 * v2;
        float u3 = 0.7978845608f * v3 + 0.0356774081f * v3 * v3 * v3;
        float e0 = exp2f(u0 * 2.8853900818f);
        float e1 = exp2f(u1 * 2.8853900818f);
        float e2 = exp2f(u2 * 2.8853900818f);
        float e3 = exp2f(u3 * 2.8853900818f);
        v0 = v0 - v0 / (e0 + 1.0f);
        v1 = v1 - v1 / (e1 + 1.0f);
        v2 = v2 - v2 / (e2 + 1.0f);
        v3 = v3 - v3 / (e3 + 1.0f);
      }
      if (EPI == 2){
        if (col0 < 2048){
          int tt = row & (T_ - 1);
          const float* rt = rtab + ((size_t)tt * 32 + ((col0 & 63) >> 1)) * 2;
          float cc0 = rt[0], ss0 = rt[1], cc1 = rt[2], ss1 = rt[3];
          float q0 = v0 * cc0 - v1 * ss0, q1 = v0 * ss0 + v1 * cc0;
          float q2 = v2 * cc1 - v3 * ss1, q3 = v2 * ss1 + v3 * cc1;
          if (col0 < 1024){
            const float qs = 0.125f * 1.44269504f;
            q0 *= qs; q1 *= qs; q2 *= qs; q3 *= qs;
          }
          v0 = q0; v1 = q1; v2 = q2; v3 = q3;
        }
      }
      uint2 ov;
      ov.x = pack2bf(v0, v1);
      ov.y = pack2bf(v2, v3);
      *(uint2*)((u16*)Cout + (size_t)row * N + col0) = ov;
    }
  }
}

// ---------------- GEMM (BM=64, BN=128, BK=64): skinny-N GEMMs (Wo, Wpr).
// 256 thr = 4 waves (2m x 2n), wave tile 32x64, swapped operands.
// BK=64 halves the per-K-work barrier/vmcnt overhead vs BK=32 (the measured
// 2-phase critical path). RING=3 (72KB -> 2 blk/CU), 6 loads/thread/tile,
// steady vmcnt(6), one barrier/iter, reads-first.
// fp32 + bias + residual output.
__global__ __launch_bounds__(256, 2) void gemm64_kernel(
    const u16* __restrict__ A, const u16* __restrict__ Bt,
    const float* __restrict__ bias, const float* __restrict__ res,
    float* __restrict__ Cout, int M, int N, int K)
{
  __shared__ __attribute__((aligned(16))) u16 As[3][64 * 64];
  __shared__ __attribute__((aligned(16))) u16 Bs[3][128 * 64];
  const int tid  = threadIdx.x;
  const int lane = tid & 63;
  const int wid  = tid >> 6;           // 0..3
  const int wm = wid >> 1, wn = wid & 1;
  const int lrow = lane & 15, lkg = lane >> 4;

  // XCD-aware bijective swizzle (nwg % 8 == 0)
  const int gx  = gridDim.x;           // N/128
  const int nwg = gx * gridDim.y;
  const int wg  = blockIdx.y * gx + blockIdx.x;
  const int nx  = nwg >> 3;
  const int swz = (wg & 7) * nx + (wg >> 3);
  const int m0 = (swz / gx) * 64, n0 = (swz % gx) * 128;

  // staging: rows have 8 chunks of 16B (K=64). thread base chunk: r=tid>>3,
  // c=tid&7; swizzle low-2 bits of chunk (invariant under r+32k strides).
  const int sr = tid >> 3;             // 0..31
  const int sc8 = tid & 7;
  const int scs = (sc8 & 4) | ((sc8 & 3) ^ ((sr >> 1) & 3));
  // A: 512 chunks -> ci = tid, tid+256 (rows sr, sr+32)
  const u16* Asrc0 = A + (size_t)(m0 + sr) * K + scs * 8;
  const u16* Asrc1 = Asrc0 + (size_t)32 * K;
  // B: 1024 chunks -> ci = tid + 256k, k=0..3 (rows sr+32k)
  const u16* Bsrc0 = Bt + (size_t)(n0 + sr) * K + scs * 8;
  const u16* Bsrc1 = Bsrc0 + (size_t)32 * K;
  const u16* Bsrc2 = Bsrc0 + (size_t)64 * K;
  const u16* Bsrc3 = Bsrc0 + (size_t)96 * K;
  const int dA0 = tid * 8,        dA1 = (tid + 256) * 8;
  const int dB0 = tid * 8,        dB1 = (tid + 256) * 8;
  const int dB2 = (tid + 512) * 8, dB3 = (tid + 768) * 8;

  // loop-invariant frag byte offsets (row stride 128B, chunk = kh*4 + swz)
  int aoff[2][2], boff[4][2];
  #pragma unroll
  for (int kh = 0; kh < 2; ++kh){
    #pragma unroll
    for (int mi = 0; mi < 2; ++mi){
      int r = wm*32 + mi*16 + lrow;
      aoff[mi][kh] = (r*8 + kh*4 + (lkg ^ ((r >> 1) & 3))) * 16;
    }
    #pragma unroll
    for (int ni = 0; ni < 4; ++ni){
      int r = wn*64 + ni*16 + lrow;
      boff[ni][kh] = (r*8 + kh*4 + (lkg ^ ((r >> 1) & 3))) * 16;
    }
  }

  f32x4 acc[2][4] = {};
  const int NT = K >> 6;

  // prologue: stage tiles 0,1 (6 loads each: A x2 then B x4)
  #pragma unroll
  for (int s = 0; s < 2; ++s){
    int k0 = s << 6;
    gload_lds16(Asrc0 + k0, &As[s][dA0]);
    gload_lds16(Asrc1 + k0, &As[s][dA1]);
    gload_lds16(Bsrc0 + k0, &Bs[s][dB0]);
    gload_lds16(Bsrc1 + k0, &Bs[s][dB1]);
    gload_lds16(Bsrc2 + k0, &Bs[s][dB2]);
    gload_lds16(Bsrc3 + k0, &Bs[s][dB3]);
  }

  int rs = 0, wsl = 2;
  for (int t = 0; t < NT; ++t){
    if (t < NT - 1) asm volatile("s_waitcnt vmcnt(6)" ::: "memory");
    else            asm volatile("s_waitcnt vmcnt(0)" ::: "memory");
    __builtin_amdgcn_s_barrier();        // tile t visible; slot wsl free

    const char* Ab = (const char*)&As[rs][0];
    const char* Bb = (const char*)&Bs[rs][0];
    rs = (rs + 1 == 3) ? 0 : rs + 1;

    // frag reads FIRST (12 b128) — compiler emits fine-grained lgkmcnt
    bf16x8 af[2][2], bfr[4][2];
    #pragma unroll
    for (int kh = 0; kh < 2; ++kh){
      #pragma unroll
      for (int mi = 0; mi < 2; ++mi)
        af[mi][kh] = *(const bf16x8*)(Ab + aoff[mi][kh]);
      #pragma unroll
      for (int ni = 0; ni < 4; ++ni)
        bfr[ni][kh] = *(const bf16x8*)(Bb + boff[ni][kh]);
    }
    __builtin_amdgcn_sched_barrier(0);   // keep stage below the reads

    if (t + 2 < NT){                     // refill slot read at iter t-1
      int k0 = (t + 2) << 6;
      gload_lds16(Asrc0 + k0, &As[wsl][dA0]);
      gload_lds16(Asrc1 + k0, &As[wsl][dA1]);
      gload_lds16(Bsrc0 + k0, &Bs[wsl][dB0]);
      gload_lds16(Bsrc1 + k0, &Bs[wsl][dB1]);
      gload_lds16(Bsrc2 + k0, &Bs[wsl][dB2]);
      gload_lds16(Bsrc3 + k0, &Bs[wsl][dB3]);
    }
    wsl = (wsl + 1 == 3) ? 0 : wsl + 1;

    // 16 MFMA (swapped operands)
    #pragma unroll
    for (int kh = 0; kh < 2; ++kh)
      #pragma unroll
      for (int mi = 0; mi < 2; ++mi)
        #pragma unroll
        for (int ni = 0; ni < 4; ++ni)
          acc[mi][ni] = __builtin_amdgcn_mfma_f32_16x16x32_bf16(
              bfr[ni][kh], af[mi][kh], acc[mi][ni], 0, 0, 0);
  }

  // epilogue: vectorized float4 (bias + residual + store)
  #pragma unroll
  for (int mi = 0; mi < 2; ++mi){
    int row = m0 + wm*32 + mi*16 + lrow;
    #pragma unroll
    for (int ni = 0; ni < 4; ++ni){
      int col0 = n0 + wn*64 + ni*16 + lkg*4;
      float4 bv = *(const float4*)(bias + col0);
      float4 rv = *(const float4*)(res + (size_t)row * N + col0);
      float4 ov;
      ov.x = acc[mi][ni][0] + bv.x + rv.x;
      ov.y = acc[mi][ni][1] + bv.y + rv.y;
      ov.z = acc[mi][ni][2] + bv.z + rv.z;
      ov.w = acc[mi][ni][3] + bv.w + rv.w;
      *(float4*)(Cout + (size_t)row * N + col0) = ov;
    }
  }
}

// ---------------- fused attention (swapped-operand form), 8 waves / 128 q-rows
__global__ __launch_bounds__(512, 4) void attn_kernel(
    const u16* __restrict__ qkv, const u16* __restrict__ vtg,
    u16* __restrict__ out)
{
  __shared__ u16 K_lds[3][64 * 64];
  __shared__ u16 VT_lds[3][64 * 64];
  __shared__ u16 P_lds[8][16 * 64];
  const int tid = threadIdx.x, lane = tid & 63, w = tid >> 6;   // w: 0..7
  const int lrow = lane & 15, lkg = lane >> 4;
  const int q0 = blockIdx.x * 128;
  const int bh = blockIdx.y, b = bh >> 4, h = bh & 15;
  const size_t baseq  = (size_t)b * T_ * QKV_S + h * HS_;
  const size_t basek  = baseq + 1024;
  const size_t basevt = (size_t)bh * HS_ * T_;
  const size_t baseo  = (size_t)b * T_ * H_ + h * HS_;
  const int qg = q0 + w * 16 + lrow;      // this lane's q row

  bf16x8 qa[2];
  {
    const u16* qp = qkv + baseq + (size_t)qg * QKV_S + lkg * 8;
    qa[0] = *(const bf16x8*)qp;
    qa[1] = *(const bf16x8*)(qp + 32);
  }

  const int r0 = tid >> 3, c0 = tid & 7, g0 = c0 ^ (r0 & 7);
  const u16* kap = qkv + basek + (size_t)r0 * QKV_S + g0 * 8;
  const u16* vap = vtg + basevt + (size_t)r0 * T_ + g0 * 8;
  const int kd = tid * 8;

  f32x4 o[4] = {};
  float mrun = -1e30f, lrun = 0.f;

  #pragma unroll
  for (int s = 0; s < 2; ++s){
    gload_lds16(kap + (size_t)s * 64 * QKV_S, &K_lds[s][kd]);
    gload_lds16(vap + s * 64,                 &VT_lds[s][kd]);
  }

  int rs = 0, wsl = 2;
  for (int t = 0; t < 16; ++t){
    const int kt = t << 6;
    if (t < 15) asm volatile("s_waitcnt vmcnt(2)" ::: "memory");
    else        asm volatile("s_waitcnt vmcnt(0)" ::: "memory");
    __builtin_amdgcn_s_barrier();
    __builtin_amdgcn_sched_barrier(0);

    if (t + 2 < 16){
      gload_lds16(kap + (size_t)(t + 2) * 64 * QKV_S, &K_lds[wsl][kd]);
      gload_lds16(vap + (t + 2) * 64,                 &VT_lds[wsl][kd]);
    }
    wsl = (wsl + 1 == 3) ? 0 : wsl + 1;

    const u16* Kc  = K_lds[rs];
    const u16* VTc = VT_lds[rs];
    rs = (rs + 1 == 3) ? 0 : rs + 1;

    f32x4 s[4];
    __builtin_amdgcn_s_setprio(1);
    #pragma unroll
    for (int mi = 0; mi < 4; ++mi){
      f32x4 c = {};
      #pragma unroll
      for (int ss = 0; ss < 2; ++ss){
        int r = mi * 16 + lrow;
        int off = r * 128 + (((ss * 4 + lkg) ^ (r & 7)) * 16);
        bf16x8 kb = *(const bf16x8*)((const char*)Kc + off);
        c = __builtin_amdgcn_mfma_f32_16x16x32_bf16(kb, qa[ss], c, 0, 0, 0);
      }
      s[mi] = c;
    }
    __builtin_amdgcn_s_setprio(0);

    float mt = fmaxf(fmaxf(fmaxf(s[0][0], s[0][1]), fmaxf(s[0][2], s[0][3])),
                     fmaxf(fmaxf(s[1][0], s[1][1]), fmaxf(s[1][2], s[1][3])));
    mt = fmaxf(mt, fmaxf(fmaxf(fmaxf(s[2][0], s[2][1]), fmaxf(s[2][2], s[2][3])),
                         fmaxf(fmaxf(s[3][0], s[3][1]), fmaxf(s[3][2], s[3][3]))));
    mt = fmaxf(mt, __shfl_xor(mt, 16));
    mt = fmaxf(mt, __shfl_xor(mt, 32));
    if (!__all(mt <= mrun + 8.f)){       // defer-max
      float mnew = fmaxf(mrun, mt);
      float fsc = exp2f(mrun - mnew);
      lrun *= fsc;
      #pragma unroll
      for (int nf = 0; nf < 4; ++nf){
        #pragma unroll
        for (int r = 0; r < 4; ++r) o[nf][r] *= fsc;
      }
      mrun = mnew;
    }

    float p[16];
    float ls = 0.f;
    #pragma unroll
    for (int mi = 0; mi < 4; ++mi){
      #pragma unroll
      for (int r = 0; r < 4; ++r){
        int key = kt + mi * 16 + lkg * 4 + r;
        float pv = exp2f(s[mi][r] - mrun);
        ls += pv;                          // denominator over ALL keys
        p[mi * 4 + r] = (key <= qg) ? pv : 0.f;
      }
    }
    ls += __shfl_xor(ls, 16);
    ls += __shfl_xor(ls, 32);
    lrun += ls;

    if (kt <= q0 + w * 16 + 15){
      char* pbase = (char*)&P_lds[w][0];
      const int rx = (lrow & 7) << 4;
      #pragma unroll
      for (int mi = 0; mi < 4; ++mi){
        uint2 pk;
        pk.x = pack2bf(p[mi*4+0], p[mi*4+1]);
        pk.y = pack2bf(p[mi*4+2], p[mi*4+3]);
        *(uint2*)(pbase + (lrow * 128 + ((mi * 32 + lkg * 8) ^ rx))) = pk;
      }
      __builtin_amdgcn_s_setprio(1);
      #pragma unroll
      for (int ss = 0; ss < 2; ++ss){
        bf16x8 pb = *(const bf16x8*)(pbase + (lrow * 128 + ((ss * 64 + lkg * 16) ^ rx)));
        #pragma unroll
        for (int nfd = 0; nfd < 4; ++nfd){
          int d = nfd * 16 + lrow;
          int off = d * 128 + (((ss * 4 + lkg) ^ (d & 7)) * 16);
          bf16x8 vb = *(const bf16x8*)((const char*)VTc + off);
          o[nfd] = __builtin_amdgcn_mfma_f32_16x16x32_bf16(vb, pb, o[nfd], 0, 0, 0);
        }
      }
      __builtin_amdgcn_s_setprio(0);
    }
  }

  float rl = 1.0f / lrun;
  #pragma unroll
  for (int nfd = 0; nfd < 4; ++nfd){
    uint2 ov;
    ov.x = pack2bf(o[nfd][0] * rl, o[nfd][1] * rl);
    ov.y = pack2bf(o[nfd][2] * rl, o[nfd][3] * rl);
    *(uint2*)(out + baseo + (size_t)qg * H_ + nfd * 16 + lkg * 4) = ov;
  }
}

extern "C" void kernel_launch(void* const* d_in, const int* in_sizes, int n_in,
                              void* d_out, int out_size, void* d_ws, size_t ws_size,
                              hipStream_t stream)
{
  (void)in_sizes; (void)n_in; (void)out_size; (void)ws_size;
  const float* x    = (const float*)d_in[0];
  const float* Wq   = (const float*)d_in[1];
  const float* bq   = (const float*)d_in[2];
  const float* Wk   = (const float*)d_in[3];
  const float* bk   = (const float*)d_in[4];
  const float* Wv   = (const float*)d_in[5];
  const float* bv   = (const float*)d_in[6];
  const float* Wo   = (const float*)d_in[7];
  const float* bo   = (const float*)d_in[8];
  const float* ln1w = (const float*)d_in[9];
  const float* ln1b = (const float*)d_in[10];
  const float* ln2w = (const float*)d_in[11];
  const float* ln2b = (const float*)d_in[12];
  const float* Wfc  = (const float*)d_in[13];
  const float* bfc  = (const float*)d_in[14];
  const float* Wpr  = (const float*)d_in[15];
  const float* bpr  = (const float*)d_in[16];

  char* ws = (char*)d_ws;
  u16*  WqkvT = (u16*)(ws + ((size_t) 0 << 20));   //  6MB [3072][1024]
  u16*  WoT   = (u16*)(ws + ((size_t) 6 << 20));   //  2MB
  u16*  WfcT  = (u16*)(ws + ((size_t) 8 << 20));   //  8MB [FF][H]
  u16*  WprT  = (u16*)(ws + ((size_t)16 << 20));   //  8MB [H][FF]
  u16*  h1    = (u16*)(ws + ((size_t)24 << 20));   //  8MB; reused as attnout
  u16*  qkvb  = (u16*)(ws + ((size_t)32 << 20));   // 24MB [M][3072]; dead after attn
  float* x1   = (float*)(ws + ((size_t)32 << 20)); // 16MB (reuses qkvb region)
  u16*  h2    = (u16*)(ws + ((size_t)48 << 20));   //  8MB (reuses qkvb region)
  float* bqkv = (float*)(ws + ((size_t)56 << 20)); // 12KB (dead before mb written)
  float* rtab = (float*)(ws + ((size_t)56 << 20) + (64 << 10)); // 256KB (dead before mb)
  u16*  vtg   = (u16*)(ws + ((size_t)57 << 20));   //  8MB (dead before mb)
  u16*  mb    = (u16*)(ws + ((size_t)56 << 20));   // 32MB (overwrites bqkv/rtab/vtg)
  u16*  attnout = h1;

  dim3 blk(256);
  dim3 gblk(512);

  // weights: transpose + bf16 (QKV concatenated; 4 HxH in one launch)
  trans_qkvo_k<<<dim3(H_/64, H_/64, 4), blk, 0, stream>>>(Wq, Wk, Wv, Wo, WqkvT, WoT);
  transpose_cvt<<<dim3(FF_/64, H_/64),  blk, 0, stream>>>(Wfc, WfcT, H_,  FF_);
  transpose_cvt<<<dim3(H_/64,  FF_/64), blk, 0, stream>>>(Wpr, WprT, FF_, H_);
  prep_small_k<<<dim3((QKV_S + T_*32 + 255)/256), blk, 0, stream>>>(bq, bk, bv, bqkv, rtab);

  // LN1
  ln_kernel<<<dim3(M_), blk, 0, stream>>>(x, ln1w, ln1b, h1);
  // fused QKV projection + RoPE — 8-phase 256x256, grid 12x16
  gemm8p_kernel<2><<<dim3(QKV_S/256, M_/256), gblk, 0, stream>>>(h1, WqkvT, bqkv, rtab, qkvb, M_, QKV_S, H_);
  // per-head V transpose
  vtrans_k<<<dim3(T_/64, B_*NH_), blk, 0, stream>>>(qkvb, vtg);
  // attention — 8 waves, 128 q-rows/block
  attn_kernel<<<dim3(T_/128, B_*NH_), dim3(512), 0, stream>>>(qkvb, vtg, attnout);
  // out projection + residual -> x1 (fp32) — BM=64/BK=64 grid 8x64 (2 blk/CU)
  gemm64_kernel<<<dim3(H_/128, M_/64), blk, 0, stream>>>(attnout, WoT, bo, x, x1, M_, H_, H_);
  // LN2
  ln_kernel<<<dim3(M_), blk, 0, stream>>>(x1, ln2w, ln2b, h2);
  // MLP — Wfc 8-phase 256x256 grid 16x16; Wpr BM=64/BK=64 grid 8x64
  gemm8p_kernel<1><<<dim3(FF_/256, M_/256), gblk, 0, stream>>>(h2, WfcT, bfc, nullptr, mb, M_, FF_, H_);
  gemm64_kernel<<<dim3(H_/128, M_/64), blk, 0, stream>>>(mb, WprT, bpr, x1, (float*)d_out, M_, H_, FF_);
}

// Round 18
// 236.731 us; speedup vs baseline: 1.1310x; 1.0101x over previous
//
#include <hip/hip_runtime.h>
#include <hip/hip_bf16.h>

typedef unsigned short u16;
typedef __attribute__((ext_vector_type(8))) short bf16x8;
typedef __attribute__((ext_vector_type(4))) float f32x4;
typedef __attribute__((ext_vector_type(4))) unsigned short u16x4;

#define B_  4
#define T_  1024
#define H_  1024
#define NH_ 16
#define HS_ 64
#define FF_ 4096
#define M_  (B_*T_)
#define QKV_S 3072

__device__ __forceinline__ u16 f2bf(float f){
  union { float f; unsigned u; } v; v.f = f;
  unsigned r = v.u + 0x7fffu + ((v.u >> 16) & 1u);
  return (u16)(r >> 16);
}
__device__ __forceinline__ float bf2f(u16 h){
  union { unsigned u; float f; } v; v.u = ((unsigned)h) << 16;
  return v.f;
}
__device__ __forceinline__ unsigned pack2bf(float a, float b){
  __hip_bfloat162 h = __float22bfloat162_rn(make_float2(a, b));
  union { __hip_bfloat162 h; unsigned u; } c; c.h = h;
  return c.u;
}
__device__ __forceinline__ float max3f(float a, float b, float c){
  return fmaxf(fmaxf(a, b), c);     // clang fuses to v_max3_f32
}

__device__ __forceinline__ void gload_lds16(const void* g, void* l){
  __builtin_amdgcn_global_load_lds(
      (const __attribute__((address_space(1))) unsigned int*)g,
      (__attribute__((address_space(3))) unsigned int*)l,
      16, 0, 0);
}

// ---------------- 64x64 transpose tile body (fp32 -> bf16)
__device__ __forceinline__ void trans_tile(const float* __restrict__ W,
                                           u16* __restrict__ Wt, int K, int N,
                                           int k0, int n0, int tid)
{
  __shared__ u16 tile[64][68];
  #pragma unroll
  for (int it = 0; it < 4; ++it){
    int ci = tid + it * 256;
    int kr = ci >> 4, nc = ci & 15;
    float4 f = *(const float4*)(W + (size_t)(k0 + kr) * N + n0 + nc * 4);
    tile[kr][nc*4+0] = f2bf(f.x);
    tile[kr][nc*4+1] = f2bf(f.y);
    tile[kr][nc*4+2] = f2bf(f.z);
    tile[kr][nc*4+3] = f2bf(f.w);
  }
  __syncthreads();
  #pragma unroll
  for (int it = 0; it < 4; ++it){
    int co = tid + it * 256;
    int nr = co >> 4, kc = co & 15;
    u16x4 o;
    o[0] = tile[kc*4+0][nr];
    o[1] = tile[kc*4+1][nr];
    o[2] = tile[kc*4+2][nr];
    o[3] = tile[kc*4+3][nr];
    *(u16x4*)(Wt + (size_t)(n0 + nr) * K + k0 + kc * 4) = o;
  }
}

// ---------------- fused 4x HxH weight transpose (Wq,Wk,Wv -> WqkvT; Wo -> WoT)
__global__ __launch_bounds__(256) void trans_qkvo_k(
    const float* __restrict__ Wq, const float* __restrict__ Wk,
    const float* __restrict__ Wv, const float* __restrict__ Wo,
    u16* __restrict__ WqkvT, u16* __restrict__ WoT)
{
  const int z = blockIdx.z;
  const float* src = (z == 0) ? Wq : (z == 1) ? Wk : (z == 2) ? Wv : Wo;
  u16* dst = (z == 3) ? WoT : (WqkvT + (size_t)z * 1024 * 1024);
  trans_tile(src, dst, H_, H_, blockIdx.y * 64, blockIdx.x * 64, threadIdx.x);
}

// ---------------- generic transpose (Wfc, Wpr)
__global__ __launch_bounds__(256) void transpose_cvt(const float* __restrict__ W,
                                                     u16* __restrict__ Wt, int K, int N)
{
  trans_tile(W, Wt, K, N, blockIdx.y * 64, blockIdx.x * 64, threadIdx.x);
}

// ---------------- per-head V transpose: vtg[bh][d][t] = v[b,t,h,d]
__global__ __launch_bounds__(256) void vtrans_k(const u16* __restrict__ qkv,
                                                u16* __restrict__ vtg)
{
  __shared__ u16 tile[64][72];
  const int bh = blockIdx.y, tt = blockIdx.x * 64;
  const int b = bh >> 4, h = bh & 15;
  const size_t src = (size_t)b * T_ * QKV_S + h * HS_ + 2048;
  const int tid = threadIdx.x;
  #pragma unroll
  for (int it = 0; it < 2; ++it){
    int ci = tid + it * 256;
    int r = ci >> 3, c = ci & 7;
    bf16x8 vvv = *(const bf16x8*)(qkv + src + (size_t)(tt + r) * QKV_S + c * 8);
    *(bf16x8*)&tile[r][c * 8] = vvv;
  }
  __syncthreads();
  #pragma unroll
  for (int it = 0; it < 2; ++it){
    int co = tid + it * 256;
    int d = co >> 3, c = co & 7;
    bf16x8 ov;
    #pragma unroll
    for (int j = 0; j < 8; ++j) ov[j] = (short)tile[c * 8 + j][d];
    *(bf16x8*)(vtg + (size_t)bh * HS_ * T_ + (size_t)d * T_ + tt + c * 8) = ov;
  }
}

// ---------------- small prep: bias concat (3072) + rope cos/sin table (32768)
__global__ void prep_small_k(const float* __restrict__ a, const float* __restrict__ b,
                             const float* __restrict__ c, float* __restrict__ o,
                             float* __restrict__ tab){
  int i = blockIdx.x * 256 + threadIdx.x;
  if (i < QKV_S){
    o[i] = (i < 1024) ? a[i] : (i < 2048) ? b[i - 1024] : c[i - 2048];
  } else {
    int j = i - QKV_S;
    if (j < T_ * 32){
      int t = j >> 5, f = j & 31;
      float inv = powf(10000.0f, -(float)f * (1.0f / 32.0f));
      float ang = (float)t * inv;
      tab[j*2+0] = cosf(ang);
      tab[j*2+1] = sinf(ang);
    }
  }
}

// ---------------- LayerNorm: fp32 in -> bf16 out, one row (1024) per block
__global__ __launch_bounds__(256) void ln_kernel(const float* __restrict__ x,
    const float* __restrict__ w, const float* __restrict__ bgain,
    u16* __restrict__ out)
{
  const int row = blockIdx.x;
  const int t = threadIdx.x;
  float4 vv = ((const float4*)(x + (size_t)row * H_))[t];
  float s  = vv.x + vv.y + vv.z + vv.w;
  float s2 = vv.x*vv.x + vv.y*vv.y + vv.z*vv.z + vv.w*vv.w;
  #pragma unroll
  for (int mm = 1; mm < 64; mm <<= 1){ s += __shfl_xor(s, mm); s2 += __shfl_xor(s2, mm); }
  __shared__ float red[8];
  int wid = t >> 6;
  if ((t & 63) == 0){ red[wid] = s; red[4 + wid] = s2; }
  __syncthreads();
  s  = red[0] + red[1] + red[2] + red[3];
  s2 = red[4] + red[5] + red[6] + red[7];
  float mu  = s * (1.0f / H_);
  float var = s2 * (1.0f / H_) - mu * mu;
  float rin = rsqrtf(var + 1e-5f);
  float4 wv = ((const float4*)w)[t];
  float4 bv = ((const float4*)bgain)[t];
  u16x4 ov;
  ov[0] = f2bf((vv.x - mu) * rin * wv.x + bv.x);
  ov[1] = f2bf((vv.y - mu) * rin * wv.y + bv.y);
  ov[2] = f2bf((vv.z - mu) * rin * wv.z + bv.z);
  ov[3] = f2bf((vv.w - mu) * rin * wv.w + bv.w);
  ((u16x4*)(out + (size_t)row * H_))[t] = ov;
}

// ---------------- GEMM 8-phase (BM=BN=256, BK=64): T3+T4 schedule.
// EPI 0: bf16. EPI 1: bf16 gelu. EPI 2: bf16 + fused RoPE (cols<2048).
template<int EPI>
__global__ __launch_bounds__(512, 1) void gemm8p_kernel(
    const u16* __restrict__ A, const u16* __restrict__ Bt,
    const float* __restrict__ bias, const float* __restrict__ rtab,
    void* __restrict__ Cout, int M, int N, int K)
{
  __shared__ __attribute__((aligned(16))) u16 Abuf[2][2][8192];
  __shared__ __attribute__((aligned(16))) u16 Bbuf[2][2][8192];
  const int tid  = threadIdx.x;
  const int lane = tid & 63;
  const int wid  = tid >> 6;           // 0..7
  const int wm = wid >> 2, wn = wid & 3;
  const int lrow = lane & 15, lkg = lane >> 4;

  const int gx  = gridDim.x;
  const int nwg = gx * gridDim.y;
  const int wg  = blockIdx.y * gx + blockIdx.x;
  const int nx  = nwg >> 3;
  const int swz = (wg & 7) * nx + (wg >> 3);
  const int m0 = (swz / gx) * 256, n0 = (swz % gx) * 256;

  const int r0 = tid >> 2, c0 = tid & 3;
  const int sc = c0 ^ ((r0 >> 1) & 3);
  const u16* As0 = A  + (size_t)(m0 + r0) * K + sc * 8;
  const u16* As1 = As0 + (size_t)128 * K;
  const u16* Bs0 = Bt + (size_t)(n0 + r0) * K + sc * 8;
  const u16* Bs1 = Bs0 + (size_t)128 * K;
  const int dlo = tid * 8, dhi = (tid + 512) * 8;

  int aoff[8], boff[4];
  #pragma unroll
  for (int mi = 0; mi < 8; ++mi){
    int r = wm*128 + mi*16 + lrow;
    aoff[mi] = (r*4 + (lkg ^ ((r >> 1) & 3))) * 16;
  }
  #pragma unroll
  for (int ni = 0; ni < 4; ++ni){
    int r = wn*64 + ni*16 + lrow;
    boff[ni] = (r*4 + (lkg ^ ((r >> 1) & 3))) * 16;
  }

  f32x4 acc[8][4] = {};
  const int NT = K >> 6;

  gload_lds16(As0,      &Abuf[0][0][dlo]); gload_lds16(As1,      &Abuf[0][0][dhi]);
  gload_lds16(Bs0,      &Bbuf[0][0][dlo]); gload_lds16(Bs1,      &Bbuf[0][0][dhi]);
  gload_lds16(As0 + 32, &Abuf[0][1][dlo]); gload_lds16(As1 + 32, &Abuf[0][1][dhi]);
  gload_lds16(Bs0 + 32, &Bbuf[0][1][dlo]); gload_lds16(Bs1 + 32, &Bbuf[0][1][dhi]);
  asm volatile("s_waitcnt vmcnt(4)" ::: "memory");
  __builtin_amdgcn_s_barrier();

  for (int t = 0; t < NT; ++t){
    const int cb = t & 1, nb = (t + 1) & 1;
    const int koff = (t + 1) << 6;
    const char* Ak0 = (const char*)&Abuf[cb][0][0];
    const char* Ak1 = (const char*)&Abuf[cb][1][0];
    const char* Bk0 = (const char*)&Bbuf[cb][0][0];
    const char* Bk1 = (const char*)&Bbuf[cb][1][0];
    const bool pre = (t + 1 < NT);
    bf16x8 af[8], bf[4];

    // ---- phase 0
    #pragma unroll
    for (int mi = 0; mi < 8; ++mi) af[mi] = *(const bf16x8*)(Ak0 + aoff[mi]);
    bf[0] = *(const bf16x8*)(Bk0 + boff[0]);
    bf[1] = *(const bf16x8*)(Bk0 + boff[1]);
    if (pre){ gload_lds16(As0 + koff, &Abuf[nb][0][dlo]);
              gload_lds16(As1 + koff, &Abuf[nb][0][dhi]); }
    __builtin_amdgcn_s_barrier();
    asm volatile("s_waitcnt lgkmcnt(0)" ::: "memory");
    __builtin_amdgcn_sched_barrier(0);
    __builtin_amdgcn_s_setprio(1);
    #pragma unroll
    for (int mi = 0; mi < 8; ++mi){
      acc[mi][0] = __builtin_amdgcn_mfma_f32_16x16x32_bf16(bf[0], af[mi], acc[mi][0], 0, 0, 0);
      acc[mi][1] = __builtin_amdgcn_mfma_f32_16x16x32_bf16(bf[1], af[mi], acc[mi][1], 0, 0, 0);
    }
    __builtin_amdgcn_s_setprio(0);
    __builtin_amdgcn_s_barrier();

    // ---- phase 1
    bf[2] = *(const bf16x8*)(Bk0 + boff[2]);
    bf[3] = *(const bf16x8*)(Bk0 + boff[3]);
    if (pre){ gload_lds16(Bs0 + koff, &Bbuf[nb][0][dlo]);
              gload_lds16(Bs1 + koff, &Bbuf[nb][0][dhi]); }
    __builtin_amdgcn_s_barrier();
    asm volatile("s_waitcnt lgkmcnt(0)" ::: "memory");
    __builtin_amdgcn_sched_barrier(0);
    __builtin_amdgcn_s_setprio(1);
    #pragma unroll
    for (int mi = 0; mi < 8; ++mi){
      acc[mi][2] = __builtin_amdgcn_mfma_f32_16x16x32_bf16(bf[2], af[mi], acc[mi][2], 0, 0, 0);
      acc[mi][3] = __builtin_amdgcn_mfma_f32_16x16x32_bf16(bf[3], af[mi], acc[mi][3], 0, 0, 0);
    }
    __builtin_amdgcn_s_setprio(0);
    if (pre) asm volatile("s_waitcnt vmcnt(4)" ::: "memory");
    else     asm volatile("s_waitcnt vmcnt(0)" ::: "memory");
    __builtin_amdgcn_s_barrier();

    // ---- phase 2
    #pragma unroll
    for (int mi = 0; mi < 8; ++mi) af[mi] = *(const bf16x8*)(Ak1 + aoff[mi]);
    bf[0] = *(const bf16x8*)(Bk1 + boff[0]);
    bf[1] = *(const bf16x8*)(Bk1 + boff[1]);
    if (pre){ gload_lds16(As0 + koff + 32, &Abuf[nb][1][dlo]);
              gload_lds16(As1 + koff + 32, &Abuf[nb][1][dhi]); }
    __builtin_amdgcn_s_barrier();
    asm volatile("s_waitcnt lgkmcnt(0)" ::: "memory");
    __builtin_amdgcn_sched_barrier(0);
    __builtin_amdgcn_s_setprio(1);
    #pragma unroll
    for (int mi = 0; mi < 8; ++mi){
      acc[mi][0] = __builtin_amdgcn_mfma_f32_16x16x32_bf16(bf[0], af[mi], acc[mi][0], 0, 0, 0);
      acc[mi][1] = __builtin_amdgcn_mfma_f32_16x16x32_bf16(bf[1], af[mi], acc[mi][1], 0, 0, 0);
    }
    __builtin_amdgcn_s_setprio(0);
    __builtin_amdgcn_s_barrier();

    // ---- phase 3
    bf[2] = *(const bf16x8*)(Bk1 + boff[2]);
    bf[3] = *(const bf16x8*)(Bk1 + boff[3]);
    if (pre){ gload_lds16(Bs0 + koff + 32, &Bbuf[nb][1][dlo]);
              gload_lds16(Bs1 + koff + 32, &Bbuf[nb][1][dhi]); }
    __builtin_amdgcn_s_barrier();
    asm volatile("s_waitcnt lgkmcnt(0)" ::: "memory");
    __builtin_amdgcn_sched_barrier(0);
    __builtin_amdgcn_s_setprio(1);
    #pragma unroll
    for (int mi = 0; mi < 8; ++mi){
      acc[mi][2] = __builtin_amdgcn_mfma_f32_16x16x32_bf16(bf[2], af[mi], acc[mi][2], 0, 0, 0);
      acc[mi][3] = __builtin_amdgcn_mfma_f32_16x16x32_bf16(bf[3], af[mi], acc[mi][3], 0, 0, 0);
    }
    __builtin_amdgcn_s_setprio(0);
    if (pre) asm volatile("s_waitcnt vmcnt(4)" ::: "memory");
    __builtin_amdgcn_s_barrier();
  }

  #pragma unroll
  for (int mi = 0; mi < 8; ++mi){
    int row = m0 + wm*128 + mi*16 + lrow;
    #pragma unroll
    for (int ni = 0; ni < 4; ++ni){
      int col0 = n0 + wn*64 + ni*16 + lkg*4;
      float4 bv = *(const float4*)(bias + col0);
      float v0 = acc[mi][ni][0] + bv.x;
      float v1 = acc[mi][ni][1] + bv.y;
      float v2 = acc[mi][ni][2] + bv.z;
      float v3 = acc[mi][ni][3] + bv.w;
      if (EPI == 1){
        float u0 = 0.7978845608f * v0 + 0.0356774081f * v0 * v0 * v0;
        float u1 = 0.7978845608f * v1 + 0.0356774081f * v1 * v1 * v1;
        float u2 = 0.7978845608f * v2 + 0.0356774081f * v2 * v2 * v2;
        float u3 = 0.7978845608f * v3 + 0.0356774081f * v3 * v3 * v3;
        float e0 = exp2f(u0 * 2.8853900818f);
        float e1 = exp2f(u1 * 2.8853900818f);
        float e2 = exp2f(u2 * 2.8853900818f);
        float e3 = exp2f(u3 * 2.8853900818f);
        v0 = v0 - v0 / (e0 + 1.0f);
        v1 = v1 - v1 / (e1 + 1.0f);
        v2 = v2 - v2 / (e2 + 1.0f);
        v3 = v3 - v3 / (e3 + 1.0f);
      }
      if (EPI == 2){
        if (col0 < 2048){
          int tt = row & (T_ - 1);
          const float* rt = rtab + ((size_t)tt * 32 + ((col0 & 63) >> 1)) * 2;
          float cc0 = rt[0], ss0 = rt[1], cc1 = rt[2], ss1 = rt[3];
          float q0 = v0 * cc0 - v1 * ss0, q1 = v0 * ss0 + v1 * cc0;
          float q2 = v2 * cc1 - v3 * ss1, q3 = v2 * ss1 + v3 * cc1;
          if (col0 < 1024){
            const float qs = 0.125f * 1.44269504f;
            q0 *= qs; q1 *= qs; q2 *= qs; q3 *= qs;
          }
          v0 = q0; v1 = q1; v2 = q2; v3 = q3;
        }
      }
      uint2 ov;
      ov.x = pack2bf(v0, v1);
      ov.y = pack2bf(v2, v3);
      *(uint2*)((u16*)Cout + (size_t)row * N + col0) = ov;
    }
  }
}

// ---------------- GEMM (BM=64, BN=128, BK=64): skinny-N GEMMs (Wo, Wpr).
// 256 thr = 4 waves (2m x 2n), wave tile 32x64, swapped operands.
// RING=3 (72KB -> 2 blk/CU), 6 loads/thread/tile, steady vmcnt(6),
// one barrier/iter, reads-first. fp32 + bias + residual output.
__global__ __launch_bounds__(256, 2) void gemm64_kernel(
    const u16* __restrict__ A, const u16* __restrict__ Bt,
    const float* __restrict__ bias, const float* __restrict__ res,
    float* __restrict__ Cout, int M, int N, int K)
{
  __shared__ __attribute__((aligned(16))) u16 As[3][64 * 64];
  __shared__ __attribute__((aligned(16))) u16 Bs[3][128 * 64];
  const int tid  = threadIdx.x;
  const int lane = tid & 63;
  const int wid  = tid >> 6;           // 0..3
  const int wm = wid >> 1, wn = wid & 1;
  const int lrow = lane & 15, lkg = lane >> 4;

  const int gx  = gridDim.x;           // N/128
  const int nwg = gx * gridDim.y;
  const int wg  = blockIdx.y * gx + blockIdx.x;
  const int nx  = nwg >> 3;
  const int swz = (wg & 7) * nx + (wg >> 3);
  const int m0 = (swz / gx) * 64, n0 = (swz % gx) * 128;

  const int sr = tid >> 3;             // 0..31
  const int sc8 = tid & 7;
  const int scs = (sc8 & 4) | ((sc8 & 3) ^ ((sr >> 1) & 3));
  const u16* Asrc0 = A + (size_t)(m0 + sr) * K + scs * 8;
  const u16* Asrc1 = Asrc0 + (size_t)32 * K;
  const u16* Bsrc0 = Bt + (size_t)(n0 + sr) * K + scs * 8;
  const u16* Bsrc1 = Bsrc0 + (size_t)32 * K;
  const u16* Bsrc2 = Bsrc0 + (size_t)64 * K;
  const u16* Bsrc3 = Bsrc0 + (size_t)96 * K;
  const int dA0 = tid * 8,        dA1 = (tid + 256) * 8;
  const int dB0 = tid * 8,        dB1 = (tid + 256) * 8;
  const int dB2 = (tid + 512) * 8, dB3 = (tid + 768) * 8;

  int aoff[2][2], boff[4][2];
  #pragma unroll
  for (int kh = 0; kh < 2; ++kh){
    #pragma unroll
    for (int mi = 0; mi < 2; ++mi){
      int r = wm*32 + mi*16 + lrow;
      aoff[mi][kh] = (r*8 + kh*4 + (lkg ^ ((r >> 1) & 3))) * 16;
    }
    #pragma unroll
    for (int ni = 0; ni < 4; ++ni){
      int r = wn*64 + ni*16 + lrow;
      boff[ni][kh] = (r*8 + kh*4 + (lkg ^ ((r >> 1) & 3))) * 16;
    }
  }

  f32x4 acc[2][4] = {};
  const int NT = K >> 6;

  #pragma unroll
  for (int s = 0; s < 2; ++s){
    int k0 = s << 6;
    gload_lds16(Asrc0 + k0, &As[s][dA0]);
    gload_lds16(Asrc1 + k0, &As[s][dA1]);
    gload_lds16(Bsrc0 + k0, &Bs[s][dB0]);
    gload_lds16(Bsrc1 + k0, &Bs[s][dB1]);
    gload_lds16(Bsrc2 + k0, &Bs[s][dB2]);
    gload_lds16(Bsrc3 + k0, &Bs[s][dB3]);
  }

  int rs = 0, wsl = 2;
  for (int t = 0; t < NT; ++t){
    if (t < NT - 1) asm volatile("s_waitcnt vmcnt(6)" ::: "memory");
    else            asm volatile("s_waitcnt vmcnt(0)" ::: "memory");
    __builtin_amdgcn_s_barrier();

    const char* Ab = (const char*)&As[rs][0];
    const char* Bb = (const char*)&Bs[rs][0];
    rs = (rs + 1 == 3) ? 0 : rs + 1;

    bf16x8 af[2][2], bfr[4][2];
    #pragma unroll
    for (int kh = 0; kh < 2; ++kh){
      #pragma unroll
      for (int mi = 0; mi < 2; ++mi)
        af[mi][kh] = *(const bf16x8*)(Ab + aoff[mi][kh]);
      #pragma unroll
      for (int ni = 0; ni < 4; ++ni)
        bfr[ni][kh] = *(const bf16x8*)(Bb + boff[ni][kh]);
    }
    __builtin_amdgcn_sched_barrier(0);

    if (t + 2 < NT){
      int k0 = (t + 2) << 6;
      gload_lds16(Asrc0 + k0, &As[wsl][dA0]);
      gload_lds16(Asrc1 + k0, &As[wsl][dA1]);
      gload_lds16(Bsrc0 + k0, &Bs[wsl][dB0]);
      gload_lds16(Bsrc1 + k0, &Bs[wsl][dB1]);
      gload_lds16(Bsrc2 + k0, &Bs[wsl][dB2]);
      gload_lds16(Bsrc3 + k0, &Bs[wsl][dB3]);
    }
    wsl = (wsl + 1 == 3) ? 0 : wsl + 1;

    #pragma unroll
    for (int kh = 0; kh < 2; ++kh)
      #pragma unroll
      for (int mi = 0; mi < 2; ++mi)
        #pragma unroll
        for (int ni = 0; ni < 4; ++ni)
          acc[mi][ni] = __builtin_amdgcn_mfma_f32_16x16x32_bf16(
              bfr[ni][kh], af[mi][kh], acc[mi][ni], 0, 0, 0);
  }

  #pragma unroll
  for (int mi = 0; mi < 2; ++mi){
    int row = m0 + wm*32 + mi*16 + lrow;
    #pragma unroll
    for (int ni = 0; ni < 4; ++ni){
      int col0 = n0 + wn*64 + ni*16 + lkg*4;
      float4 bv = *(const float4*)(bias + col0);
      float4 rv = *(const float4*)(res + (size_t)row * N + col0);
      float4 ov;
      ov.x = acc[mi][ni][0] + bv.x + rv.x;
      ov.y = acc[mi][ni][1] + bv.y + rv.y;
      ov.z = acc[mi][ni][2] + bv.z + rv.z;
      ov.w = acc[mi][ni][3] + bv.w + rv.w;
      *(float4*)(Cout + (size_t)row * N + col0) = ov;
    }
  }
}

// ---------------- fused attention (swapped-operand form), 8 waves / 128 q-rows
// Ring-2 K/V (48KB LDS -> 3 blocks/CU = 6 waves/SIMD), two barriers/tile:
// stage t+2 into buf[cur] AFTER the read-complete barrier; steady vmcnt(2).
// max3-fused max tree, pairwise denominator sum.
__global__ __launch_bounds__(512, 6) void attn_kernel(
    const u16* __restrict__ qkv, const u16* __restrict__ vtg,
    u16* __restrict__ out)
{
  __shared__ u16 K_lds[2][64 * 64];
  __shared__ u16 VT_lds[2][64 * 64];
  __shared__ u16 P_lds[8][16 * 64];
  const int tid = threadIdx.x, lane = tid & 63, w = tid >> 6;   // w: 0..7
  const int lrow = lane & 15, lkg = lane >> 4;
  const int q0 = blockIdx.x * 128;
  const int bh = blockIdx.y, b = bh >> 4, h = bh & 15;
  const size_t baseq  = (size_t)b * T_ * QKV_S + h * HS_;
  const size_t basek  = baseq + 1024;
  const size_t basevt = (size_t)bh * HS_ * T_;
  const size_t baseo  = (size_t)b * T_ * H_ + h * HS_;
  const int qg = q0 + w * 16 + lrow;      // this lane's q row

  bf16x8 qa[2];
  {
    const u16* qp = qkv + baseq + (size_t)qg * QKV_S + lkg * 8;
    qa[0] = *(const bf16x8*)qp;
    qa[1] = *(const bf16x8*)(qp + 32);
  }

  const int r0 = tid >> 3, c0 = tid & 7, g0 = c0 ^ (r0 & 7);
  const u16* kap = qkv + basek + (size_t)r0 * QKV_S + g0 * 8;
  const u16* vap = vtg + basevt + (size_t)r0 * T_ + g0 * 8;
  const int kd = tid * 8;

  f32x4 o[4] = {};
  float mrun = -1e30f, lrun = 0.f;

  // prologue: stage tiles 0,1 (K then V each, 2 loads/thread/tile)
  #pragma unroll
  for (int s = 0; s < 2; ++s){
    gload_lds16(kap + (size_t)s * 64 * QKV_S, &K_lds[s][kd]);
    gload_lds16(vap + s * 64,                 &VT_lds[s][kd]);
  }

  int cur = 0;
  for (int t = 0; t < 16; ++t){
    const int kt = t << 6;
    if (t < 15) asm volatile("s_waitcnt vmcnt(2)" ::: "memory");
    else        asm volatile("s_waitcnt vmcnt(0)" ::: "memory");
    __builtin_amdgcn_s_barrier();                 // tile t visible
    __builtin_amdgcn_sched_barrier(0);

    const u16* Kc  = K_lds[cur];
    const u16* VTc = VT_lds[cur];

    f32x4 s[4];
    __builtin_amdgcn_s_setprio(1);
    #pragma unroll
    for (int mi = 0; mi < 4; ++mi){
      f32x4 c = {};
      #pragma unroll
      for (int ss = 0; ss < 2; ++ss){
        int r = mi * 16 + lrow;
        int off = r * 128 + (((ss * 4 + lkg) ^ (r & 7)) * 16);
        bf16x8 kb = *(const bf16x8*)((const char*)Kc + off);
        c = __builtin_amdgcn_mfma_f32_16x16x32_bf16(kb, qa[ss], c, 0, 0, 0);
      }
      s[mi] = c;
    }
    __builtin_amdgcn_s_setprio(0);

    // max via v_max3-fusable triples (depth 3)
    float t0 = max3f(s[0][0], s[0][1], s[0][2]);
    float t1 = max3f(s[0][3], s[1][0], s[1][1]);
    float t2 = max3f(s[1][2], s[1][3], s[2][0]);
    float t3 = max3f(s[2][1], s[2][2], s[2][3]);
    float t4 = max3f(s[3][0], s[3][1], s[3][2]);
    float mt = fmaxf(max3f(t0, t1, t2), max3f(t3, t4, s[3][3]));
    mt = fmaxf(mt, __shfl_xor(mt, 16));
    mt = fmaxf(mt, __shfl_xor(mt, 32));
    if (!__all(mt <= mrun + 8.f)){       // defer-max
      float mnew = fmaxf(mrun, mt);
      float fsc = exp2f(mrun - mnew);
      lrun *= fsc;
      #pragma unroll
      for (int nf = 0; nf < 4; ++nf){
        #pragma unroll
        for (int r = 0; r < 4; ++r) o[nf][r] *= fsc;
      }
      mrun = mnew;
    }

    float pv[16];
    #pragma unroll
    for (int mi = 0; mi < 4; ++mi){
      #pragma unroll
      for (int r = 0; r < 4; ++r)
        pv[mi * 4 + r] = exp2f(s[mi][r] - mrun);
    }
    // pairwise tree sum of ALL keys (denominator), depth 4
    float a0 = (pv[0] + pv[1]) + (pv[2] + pv[3]);
    float a1 = (pv[4] + pv[5]) + (pv[6] + pv[7]);
    float a2 = (pv[8] + pv[9]) + (pv[10] + pv[11]);
    float a3 = (pv[12] + pv[13]) + (pv[14] + pv[15]);
    float ls = (a0 + a1) + (a2 + a3);
    ls += __shfl_xor(ls, 16);
    ls += __shfl_xor(ls, 32);
    lrun += ls;

    float p[16];
    #pragma unroll
    for (int mi = 0; mi < 4; ++mi){
      #pragma unroll
      for (int r = 0; r < 4; ++r){
        int key = kt + mi * 16 + lkg * 4 + r;
        p[mi * 4 + r] = (key <= qg) ? pv[mi * 4 + r] : 0.f;
      }
    }

    if (kt <= q0 + w * 16 + 15){
      char* pbase = (char*)&P_lds[w][0];
      const int rx = (lrow & 7) << 4;
      #pragma unroll
      for (int mi = 0; mi < 4; ++mi){
        uint2 pk;
        pk.x = pack2bf(p[mi*4+0], p[mi*4+1]);
        pk.y = pack2bf(p[mi*4+2], p[mi*4+3]);
        *(uint2*)(pbase + (lrow * 128 + ((mi * 32 + lkg * 8) ^ rx))) = pk;
      }
      __builtin_amdgcn_s_setprio(1);
      #pragma unroll
      for (int ss = 0; ss < 2; ++ss){
        bf16x8 pb = *(const bf16x8*)(pbase + (lrow * 128 + ((ss * 64 + lkg * 16) ^ rx)));
        #pragma unroll
        for (int nfd = 0; nfd < 4; ++nfd){
          int d = nfd * 16 + lrow;
          int off = d * 128 + (((ss * 4 + lkg) ^ (d & 7)) * 16);
          bf16x8 vb = *(const bf16x8*)((const char*)VTc + off);
          o[nfd] = __builtin_amdgcn_mfma_f32_16x16x32_bf16(vb, pb, o[nfd], 0, 0, 0);
        }
      }
      __builtin_amdgcn_s_setprio(0);
    }

    __builtin_amdgcn_s_barrier();                 // all waves done reading buf[cur]
    if (t + 2 < 16){                              // refill the slot just freed
      gload_lds16(kap + (size_t)(t + 2) * 64 * QKV_S, &K_lds[cur][kd]);
      gload_lds16(vap + (t + 2) * 64,                 &VT_lds[cur][kd]);
    }
    cur ^= 1;
  }

  float rl = 1.0f / lrun;
  #pragma unroll
  for (int nfd = 0; nfd < 4; ++nfd){
    uint2 ov;
    ov.x = pack2bf(o[nfd][0] * rl, o[nfd][1] * rl);
    ov.y = pack2bf(o[nfd][2] * rl, o[nfd][3] * rl);
    *(uint2*)(out + baseo + (size_t)qg * H_ + nfd * 16 + lkg * 4) = ov;
  }
}

extern "C" void kernel_launch(void* const* d_in, const int* in_sizes, int n_in,
                              void* d_out, int out_size, void* d_ws, size_t ws_size,
                              hipStream_t stream)
{
  (void)in_sizes; (void)n_in; (void)out_size; (void)ws_size;
  const float* x    = (const float*)d_in[0];
  const float* Wq   = (const float*)d_in[1];
  const float* bq   = (const float*)d_in[2];
  const float* Wk   = (const float*)d_in[3];
  const float* bk   = (const float*)d_in[4];
  const float* Wv   = (const float*)d_in[5];
  const float* bv   = (const float*)d_in[6];
  const float* Wo   = (const float*)d_in[7];
  const float* bo   = (const float*)d_in[8];
  const float* ln1w = (const float*)d_in[9];
  const float* ln1b = (const float*)d_in[10];
  const float* ln2w = (const float*)d_in[11];
  const float* ln2b = (const float*)d_in[12];
  const float* Wfc  = (const float*)d_in[13];
  const float* bfc  = (const float*)d_in[14];
  const float* Wpr  = (const float*)d_in[15];
  const float* bpr  = (const float*)d_in[16];

  char* ws = (char*)d_ws;
  u16*  WqkvT = (u16*)(ws + ((size_t) 0 << 20));   //  6MB [3072][1024]
  u16*  WoT   = (u16*)(ws + ((size_t) 6 << 20));   //  2MB
  u16*  WfcT  = (u16*)(ws + ((size_t) 8 << 20));   //  8MB [FF][H]
  u16*  WprT  = (u16*)(ws + ((size_t)16 << 20));   //  8MB [H][FF]
  u16*  h1    = (u16*)(ws + ((size_t)24 << 20));   //  8MB; reused as attnout
  u16*  qkvb  = (u16*)(ws + ((size_t)32 << 20));   // 24MB [M][3072]; dead after attn
  float* x1   = (float*)(ws + ((size_t)32 << 20)); // 16MB (reuses qkvb region)
  u16*  h2    = (u16*)(ws + ((size_t)48 << 20));   //  8MB (reuses qkvb region)
  float* bqkv = (float*)(ws + ((size_t)56 << 20)); // 12KB (dead before mb written)
  float* rtab = (float*)(ws + ((size_t)56 << 20) + (64 << 10)); // 256KB (dead before mb)
  u16*  vtg   = (u16*)(ws + ((size_t)57 << 20));   //  8MB (dead before mb)
  u16*  mb    = (u16*)(ws + ((size_t)56 << 20));   // 32MB (overwrites bqkv/rtab/vtg)
  u16*  attnout = h1;

  dim3 blk(256);
  dim3 gblk(512);

  // weights: transpose + bf16 (QKV concatenated; 4 HxH in one launch)
  trans_qkvo_k<<<dim3(H_/64, H_/64, 4), blk, 0, stream>>>(Wq, Wk, Wv, Wo, WqkvT, WoT);
  transpose_cvt<<<dim3(FF_/64, H_/64),  blk, 0, stream>>>(Wfc, WfcT, H_,  FF_);
  transpose_cvt<<<dim3(H_/64,  FF_/64), blk, 0, stream>>>(Wpr, WprT, FF_, H_);
  prep_small_k<<<dim3((QKV_S + T_*32 + 255)/256), blk, 0, stream>>>(bq, bk, bv, bqkv, rtab);

  // LN1
  ln_kernel<<<dim3(M_), blk, 0, stream>>>(x, ln1w, ln1b, h1);
  // fused QKV projection + RoPE — 8-phase 256x256, grid 12x16
  gemm8p_kernel<2><<<dim3(QKV_S/256, M_/256), gblk, 0, stream>>>(h1, WqkvT, bqkv, rtab, qkvb, M_, QKV_S, H_);
  // per-head V transpose
  vtrans_k<<<dim3(T_/64, B_*NH_), blk, 0, stream>>>(qkvb, vtg);
  // attention — 8 waves, 128 q-rows/block, ring-2 (3 blk/CU)
  attn_kernel<<<dim3(T_/128, B_*NH_), dim3(512), 0, stream>>>(qkvb, vtg, attnout);
  // out projection + residual -> x1 (fp32) — BM=64/BK=64 grid 8x64 (2 blk/CU)
  gemm64_kernel<<<dim3(H_/128, M_/64), blk, 0, stream>>>(attnout, WoT, bo, x, x1, M_, H_, H_);
  // LN2
  ln_kernel<<<dim3(M_), blk, 0, stream>>>(x1, ln2w, ln2b, h2);
  // MLP — Wfc 8-phase 256x256 grid 16x16; Wpr BM=64/BK=64 grid 8x64
  gemm8p_kernel<1><<<dim3(FF_/256, M_/256), gblk, 0, stream>>>(h2, WfcT, bfc, nullptr, mb, M_, FF_, H_);
  gemm64_kernel<<<dim3(H_/128, M_/64), blk, 0, stream>>>(mb, WprT, bpr, x1, (float*)d_out, M_, H_, FF_);
}